// Round 2
// 650.332 us; speedup vs baseline: 1.0423x; 1.0423x over previous
//
#include <hip/hip_runtime.h>

// ---------------- problem constants ----------------
#define BATCH 16
#define SEQ   1024
#define EMBED 1280
#define NH    16
#define HD    80
#define HDP   96           // HD padded to 3*32 for MFMA K-steps
#define NQKV  3840
#define MTOK  (BATCH*SEQ)  // 16384
#define SCALE 0.11180339887498948f
#define LOG2E 1.4426950408889634f

// LDS strides padded to kill bank conflicts (keep 16B alignment for b128 reads)
#define SK_STRIDE 104      // 52 dwords
#define SV_STRIDE 72       // 36 dwords
#define SP_STRIDE 72

typedef _Float16 half8 __attribute__((ext_vector_type(8)));
typedef _Float16 half4 __attribute__((ext_vector_type(4)));
typedef float floatx4 __attribute__((ext_vector_type(4)));

#define GLD_TO_LDS(gp, lp)                                                        \
  __builtin_amdgcn_global_load_lds(                                               \
      (const __attribute__((address_space(1))) void*)(gp),                        \
      (__attribute__((address_space(3))) void*)(lp), 16, 0, 0)

// 16-lane all-reduce max on the VALU pipe (DPP)
__device__ __forceinline__ float rowmax16(float x) {
#define DPP_MAX(ctrl)                                                             \
  {                                                                               \
    float y = __int_as_float(                                                     \
        __builtin_amdgcn_update_dpp(0, __float_as_int(x), ctrl, 0xF, 0xF, true)); \
    x = fmaxf(x, y);                                                              \
  }
  DPP_MAX(0xB1);   // quad_perm [1,0,3,2]  (xor1)
  DPP_MAX(0x4E);   // quad_perm [2,3,0,1]  (xor2)
  DPP_MAX(0x141);  // row_half_mirror      (xor4 after uniform mod 4)
  DPP_MAX(0x140);  // row_mirror           (xor8 after uniform mod 8)
#undef DPP_MAX
  return x;
}

// ---------------- converts ----------------
__global__ void cvt_f32_to_f16(const float4* __restrict__ in, _Float16* __restrict__ out, int n4) {
  int i = blockIdx.x * blockDim.x + threadIdx.x;
  if (i < n4) {
    float4 v = in[i];
    half4 h;
    h[0] = (_Float16)v.x; h[1] = (_Float16)v.y; h[2] = (_Float16)v.z; h[3] = (_Float16)v.w;
    *(half4*)(out + (size_t)i * 4) = h;
  }
}

// in [K=1280 x N] fp32 row-major -> out [N x 1280] f16, LDS-tiled (coalesced both sides)
template <int N>
__global__ void cvt_transpose_f16(const float* __restrict__ in, _Float16* __restrict__ out) {
  __shared__ float tile[32][33];
  const int tx = threadIdx.x & 31, ty = threadIdx.x >> 5;  // 256 thr: ty 0..7
  const int k0 = blockIdx.y * 32;
  const int n0 = blockIdx.x * 32;
#pragma unroll
  for (int j = 0; j < 4; ++j)
    tile[ty + 8 * j][tx] = in[(size_t)(k0 + ty + 8 * j) * N + n0 + tx];
  __syncthreads();
#pragma unroll
  for (int j = 0; j < 4; ++j)
    out[(size_t)(n0 + ty + 8 * j) * 1280 + k0 + tx] = (_Float16)tile[tx][ty + 8 * j];
}

// ---------------- 256x256 8-phase GEMM (T2 swizzle + T3/T4 counted vmcnt + T5 setprio) ----
// A [M x 1280] f16 row-major, Bt [N x 1280] f16 row-major (B transposed).
// 512 thr = 8 waves (2M x 4N); per-wave C = 128x64 as 8x4 16x16 frags.
// LDS: 2 dbuf x (256x64) x {A,B} f16 = 128 KiB. K = 1280 -> 20 K-tiles of BK=64.
// LDS layout (per tile, per matrix): elem(row,col) at row*64 + ((col>>3)^(row&7))*8 + (col&7)
//   -> ds_read_b128 of a fragment is 2-way bank aliased (free);
//   -> global_load_lds dest stays LINEAR (1 KiB per wave-inst = 8 rows), the XOR is applied
//      to the per-lane GLOBAL source chunk index (both-sides-or-neither rule).
// Stage schedule per tile t (1 half-tile = 2 gld_lds/thread):
//   q0: A-h1(t+1); q2: B-h0(t+2); q3: A-h0(t+2) + B-h1(t+2); then s_waitcnt vmcnt(6)
//   -> every half-tile is published (vmcnt+barrier) >= 1 tile before its first ds_read,
//      and no in-flight DMA ever targets the buffer region still being read.

#define STAGE_A(H, T, D)                                                           \
  do {                                                                             \
    GLD_TO_LDS(aSrc0 + (size_t)((H) * 128) * 1280 + (T) * 64,                      \
               &sA[D][((H) * 128 + wave * 16) * 64]);                              \
    GLD_TO_LDS(aSrc0 + (size_t)((H) * 128 + 8) * 1280 + (T) * 64,                  \
               &sA[D][((H) * 128 + wave * 16 + 8) * 64]);                          \
  } while (0)

#define STAGE_B(H, T, D)                                                           \
  do {                                                                             \
    GLD_TO_LDS(bSrc0 + (size_t)((H) * 128) * 1280 + (T) * 64,                      \
               &sB[D][((H) * 128 + wave * 16) * 64]);                              \
    GLD_TO_LDS(bSrc0 + (size_t)((H) * 128 + 8) * 1280 + (T) * 64,                  \
               &sB[D][((H) * 128 + wave * 16 + 8) * 64]);                          \
  } while (0)

#define LDS_FRAG(P, ROWB, FR, KK) (*(const half8*)((P) + ((ROWB) + (FR) * 16) * 64 + cofs[KK]))

#define MFMA_Q(MIB, NIB)                                                           \
  _Pragma("unroll") for (int mi = 0; mi < 4; ++mi)                                 \
    _Pragma("unroll") for (int ni = 0; ni < 2; ++ni)                               \
      _Pragma("unroll") for (int kk = 0; kk < 2; ++kk)                             \
        acc[(MIB) + mi][(NIB) + ni] = __builtin_amdgcn_mfma_f32_16x16x32_f16(      \
            af[mi][kk], bf[(NIB) + ni][kk], acc[(MIB) + mi][(NIB) + ni], 0, 0, 0)

#define GBODY(T, D, S1, S2, VNSTR)                                                 \
  {                                                                                \
    const _Float16* pA = &sA[D][0];                                                \
    const _Float16* pB = &sB[D][0];                                                \
    /* ---- q0: frags A m0-3 + B n0-1; stage A-h1(T+1) ---- */                     \
    _Pragma("unroll") for (int mi = 0; mi < 4; ++mi)                               \
      _Pragma("unroll") for (int kk = 0; kk < 2; ++kk)                             \
        af[mi][kk] = LDS_FRAG(pA, rA, mi, kk);                                     \
    _Pragma("unroll") for (int ni = 0; ni < 2; ++ni)                               \
      _Pragma("unroll") for (int kk = 0; kk < 2; ++kk)                             \
        bf[ni][kk] = LDS_FRAG(pB, rB, ni, kk);                                     \
    if (S1) { STAGE_A(1, (T) + 1, (D) ^ 1); }                                      \
    __builtin_amdgcn_s_barrier();                                                  \
    asm volatile("s_waitcnt lgkmcnt(0)" ::: "memory");                             \
    __builtin_amdgcn_s_setprio(1);                                                 \
    MFMA_Q(0, 0);                                                                  \
    __builtin_amdgcn_s_setprio(0);                                                 \
    __builtin_amdgcn_s_barrier();                                                  \
    /* ---- q1: frags B n2-3 ---- */                                               \
    _Pragma("unroll") for (int ni = 0; ni < 2; ++ni)                               \
      _Pragma("unroll") for (int kk = 0; kk < 2; ++kk)                             \
        bf[2 + ni][kk] = LDS_FRAG(pB, rB, 2 + ni, kk);                             \
    __builtin_amdgcn_s_barrier();                                                  \
    asm volatile("s_waitcnt lgkmcnt(0)" ::: "memory");                             \
    __builtin_amdgcn_s_setprio(1);                                                 \
    MFMA_Q(0, 2);                                                                  \
    __builtin_amdgcn_s_setprio(0);                                                 \
    __builtin_amdgcn_s_barrier();                                                  \
    /* ---- q2: frags A m4-7; stage B-h0(T+2) ---- */                              \
    _Pragma("unroll") for (int mi = 0; mi < 4; ++mi)                               \
      _Pragma("unroll") for (int kk = 0; kk < 2; ++kk)                             \
        af[mi][kk] = LDS_FRAG(pA, rA, 4 + mi, kk);                                 \
    if (S2) { STAGE_B(0, (T) + 2, (D)); }                                          \
    __builtin_amdgcn_s_barrier();                                                  \
    asm volatile("s_waitcnt lgkmcnt(0)" ::: "memory");                             \
    __builtin_amdgcn_s_setprio(1);                                                 \
    MFMA_Q(4, 0);                                                                  \
    __builtin_amdgcn_s_setprio(0);                                                 \
    __builtin_amdgcn_s_barrier();                                                  \
    /* ---- q3: pure MFMA; stage A-h0(T+2)+B-h1(T+2); counted vmcnt ---- */        \
    if (S2) { STAGE_A(0, (T) + 2, (D)); STAGE_B(1, (T) + 2, (D)); }                \
    __builtin_amdgcn_s_barrier();                                                  \
    __builtin_amdgcn_s_setprio(1);                                                 \
    MFMA_Q(4, 2);                                                                  \
    __builtin_amdgcn_s_setprio(0);                                                 \
    asm volatile("s_waitcnt " VNSTR ::: "memory");                                 \
    __builtin_amdgcn_s_barrier();                                                  \
  }

template <int MODE>
__global__ __launch_bounds__(512, 2)
void gemm256(const _Float16* __restrict__ A, const _Float16* __restrict__ Bt,
             const float* __restrict__ bias,
             _Float16* __restrict__ q_pad, _Float16* __restrict__ k_pad,
             _Float16* __restrict__ v_t, float* __restrict__ outf) {
  __shared__ __align__(16) _Float16 sA[2][256 * 64];  // 64 KiB
  __shared__ __align__(16) _Float16 sB[2][256 * 64];  // 64 KiB

  const int tid = threadIdx.x;
  const int wave = tid >> 6, lane = tid & 63, quad = lane >> 4, r16 = lane & 15;
  const int wm = wave >> 2, wn = wave & 3;

  // XCD-contiguous swizzle: 64 m-tiles = 8 XCDs x 8; grid %% 8 == 0 for both MODEs.
  const int pid = blockIdx.x;
  const int xcd = pid & 7, local = pid >> 3;
  const int mt = xcd * 8 + (local & 7);
  const int nt = local >> 3;
  const int m0 = mt * 256, n0 = nt * 256;

  // staging source: row_local = wave*16 + i*8 + (lane>>3); chunk = (lane&7) ^ (lane>>3)
  const int l8 = lane >> 3, cg = (lane & 7) ^ l8;
  const _Float16* aSrc0 = A + ((size_t)m0 + wave * 16 + l8) * 1280 + cg * 8;
  const _Float16* bSrc0 = Bt + ((size_t)n0 + wave * 16 + l8) * 1280 + cg * 8;

  // fragment read bases (row&7 == r16&7 since frag rows are 16-aligned + r16)
  const int rA = wm * 128 + r16;
  const int rB = wn * 64 + r16;
  const int cofs[2] = { ((0 + quad) ^ (r16 & 7)) * 8, ((4 + quad) ^ (r16 & 7)) * 8 };

  floatx4 acc[8][4] = {};
  half8 af[4][2], bf[4][2];

  // prologue: tile0 full + tile1 (B-h0, A-h0, B-h1); A-h1(1) staged at (0,q0)
  STAGE_A(0, 0, 0); STAGE_A(1, 0, 0); STAGE_B(0, 0, 0); STAGE_B(1, 0, 0);
  STAGE_B(0, 1, 1); STAGE_A(0, 1, 1); STAGE_B(1, 1, 1);
  asm volatile("s_waitcnt vmcnt(6)" ::: "memory");  // tile0 landed; tile1 may be in flight
  __builtin_amdgcn_s_barrier();

  for (int it = 0; it < 9; ++it) {
    GBODY(2 * it, 0, true, true, "vmcnt(6)");
    GBODY(2 * it + 1, 1, true, true, "vmcnt(6)");
  }
  GBODY(18, 0, true, false, "vmcnt(0)");   // drain: A-h1(19) must land before t=19 reads
  GBODY(19, 1, false, false, "vmcnt(0)");

  // ---------------- epilogue ----------------
  if (MODE == 1) {
#pragma unroll
    for (int mi = 0; mi < 8; ++mi)
#pragma unroll
      for (int ni = 0; ni < 4; ++ni) {
        int n = n0 + wn * 64 + ni * 16 + r16;
        float bv = bias[n];
#pragma unroll
        for (int r = 0; r < 4; ++r) {
          int m = m0 + wm * 128 + mi * 16 + quad * 4 + r;
          outf[(size_t)m * EMBED + n] = acc[mi][ni][r] + bv;
        }
      }
  } else {
#pragma unroll
    for (int mi = 0; mi < 8; ++mi)
#pragma unroll
      for (int ni = 0; ni < 4; ++ni) {
        int n = n0 + wn * 64 + ni * 16 + r16;
        float bv = bias[n];
        int which = n / 1280;
        int rem = n - which * 1280;
        int h = rem / 80;
        int d = rem - h * 80;
#pragma unroll
        for (int r = 0; r < 4; ++r) {
          int m = m0 + wm * 128 + mi * 16 + quad * 4 + r;
          int b = m >> 10, s = m & 1023;
          int bh = b * NH + h;
          _Float16 val = (_Float16)(acc[mi][ni][r] + bv);
          if (which == 0) {
            q_pad[((size_t)bh * SEQ + s) * HDP + d] = val;
            if (d < 16) q_pad[((size_t)bh * SEQ + s) * HDP + 80 + d] = (_Float16)0.f;
          } else if (which == 1) {
            k_pad[((size_t)bh * SEQ + s) * HDP + d] = val;
            if (d < 16) k_pad[((size_t)bh * SEQ + s) * HDP + 80 + d] = (_Float16)0.f;
          } else {
            v_t[((size_t)bh * HD + d) * SEQ + s] = val;
          }
        }
      }
  }
}

// ---------------- flash attention ----------------
// grid: (BATCH*NH) * (SEQ/128) blocks, 256 thr. wave w owns q-rows [q0+w*32, +32) (mi=0,1).
// sV has 96 d-rows: rows 0..79 = V^T tile, row 80 = ones (row-sum trick), 81..95 = 0.
// Staging: load -> immediate LDS store (transient regs only — NO cross-iter prefetch,
// R4's persistent prefetch spilled to scratch: 700 MB of HBM writes).
__global__ __launch_bounds__(256, 2)
void attn_kernel(const _Float16* __restrict__ q_pad, const _Float16* __restrict__ k_pad,
                 const _Float16* __restrict__ v_t, _Float16* __restrict__ attn_out) {
  __shared__ __align__(16) _Float16 sK[64 * SK_STRIDE];      // 13.0 KB
  __shared__ __align__(16) _Float16 sV[96 * SV_STRIDE];      // 13.5 KB
  __shared__ __align__(16) _Float16 sP[4][16 * SP_STRIDE];   //  9.0 KB (reused mi=0 then mi=1)

  const int tid = threadIdx.x;
  const int wave = tid >> 6, lane = tid & 63, quad = lane >> 4, r16 = lane & 15;
  const int bh = blockIdx.x >> 3;
  const int q0 = (blockIdx.x & 7) * 128;

  // static sV rows 80..95 (ones row + zeros), written once; never overwritten in-loop
  if (tid < 128) {
    int row = 80 + (tid >> 3), col = (tid & 7) * 8;
    half8 z;
#pragma unroll
    for (int j = 0; j < 8; ++j) z[j] = (row == 80) ? (_Float16)1.f : (_Float16)0.f;
    *(half8*)(sV + row * SV_STRIDE + col) = z;
  }

  // Q fragments (A-layout), pre-scaled by SCALE*LOG2E (log2-domain softmax)
  half8 qf[2][3];
#pragma unroll
  for (int mi = 0; mi < 2; ++mi) {
    const _Float16* qb = q_pad + ((size_t)bh * SEQ + q0 + wave * 32 + mi * 16 + r16) * HDP;
#pragma unroll
    for (int kq = 0; kq < 3; ++kq) {
      half8 q = *(const half8*)(qb + kq * 32 + quad * 8);
#pragma unroll
      for (int j = 0; j < 8; ++j) q[j] = q[j] * (_Float16)(SCALE * LOG2E);
      qf[mi][kq] = q;
    }
  }

  // per-thread staging slots
  int rowK[3], colK[3];
#pragma unroll
  for (int i = 0; i < 3; ++i) {
    int c = tid + i * 256;
    rowK[i] = c / 12; colK[i] = c - rowK[i] * 12;
  }
  const int rowV0 = tid >> 3, colV0 = tid & 7;
  const _Float16* kgb = k_pad + ((size_t)bh * SEQ) * HDP;
  const _Float16* vgb = v_t + (size_t)bh * HD * SEQ;

  floatx4 o[2][6] = {};
  float mrow[2][4];
#pragma unroll
  for (int mi = 0; mi < 2; ++mi)
#pragma unroll
    for (int r = 0; r < 4; ++r) mrow[mi][r] = -1e30f;

  for (int kt = 0; kt < 16; ++kt) {
    __syncthreads();  // prev compute done in all waves -> LDS free
    {
      // load -> store immediately (transient regs; compiler overlaps via vmcnt)
      uint4 tk0 = *(const uint4*)(kgb + ((size_t)(kt * 64 + rowK[0])) * HDP + colK[0] * 8);
      uint4 tk1 = *(const uint4*)(kgb + ((size_t)(kt * 64 + rowK[1])) * HDP + colK[1] * 8);
      uint4 tk2 = *(const uint4*)(kgb + ((size_t)(kt * 64 + rowK[2])) * HDP + colK[2] * 8);
      uint4 tv0 = *(const uint4*)(vgb + (size_t)(rowV0) * SEQ + kt * 64 + colV0 * 8);
      uint4 tv1 = *(const uint4*)(vgb + (size_t)(rowV0 + 32) * SEQ + kt * 64 + colV0 * 8);
      uint4 tv2;
      if (tid < 128)
        tv2 = *(const uint4*)(vgb + (size_t)(rowV0 + 64) * SEQ + kt * 64 + colV0 * 8);
      *(uint4*)(sK + rowK[0] * SK_STRIDE + colK[0] * 8) = tk0;
      *(uint4*)(sK + rowK[1] * SK_STRIDE + colK[1] * 8) = tk1;
      *(uint4*)(sK + rowK[2] * SK_STRIDE + colK[2] * 8) = tk2;
      *(uint4*)(sV + (rowV0) * SV_STRIDE + colV0 * 8) = tv0;
      *(uint4*)(sV + (rowV0 + 32) * SV_STRIDE + colV0 * 8) = tv1;
      if (tid < 128)
        *(uint4*)(sV + (rowV0 + 64) * SV_STRIDE + colV0 * 8) = tv2;
    }
    __syncthreads();

    // S = Q K^T : 32 q-rows x 64 keys per wave
    floatx4 sacc[2][4] = {};
#pragma unroll
    for (int ni = 0; ni < 4; ++ni)
#pragma unroll
      for (int kq = 0; kq < 3; ++kq) {
        half8 kf = *(const half8*)(sK + (ni * 16 + r16) * SK_STRIDE + kq * 32 + quad * 8);
#pragma unroll
        for (int mi = 0; mi < 2; ++mi)
          sacc[mi][ni] = __builtin_amdgcn_mfma_f32_16x16x32_f16(qf[mi][kq], kf, sacc[mi][ni], 0, 0, 0);
      }

    // online softmax (log2 domain); sums via ones-row MFMA, max via DPP
#pragma unroll
    for (int mi = 0; mi < 2; ++mi)
#pragma unroll
      for (int r = 0; r < 4; ++r) {
        float mx = fmaxf(fmaxf(sacc[mi][0][r], sacc[mi][1][r]),
                         fmaxf(sacc[mi][2][r], sacc[mi][3][r]));
        mx = rowmax16(mx);
        float mnew = fmaxf(mrow[mi][r], mx);
        float alpha = __builtin_amdgcn_exp2f(mrow[mi][r] - mnew);
        mrow[mi][r] = mnew;
#pragma unroll
        for (int ni = 0; ni < 4; ++ni)
          sacc[mi][ni][r] = __builtin_amdgcn_exp2f(sacc[mi][ni][r] - mnew);
#pragma unroll
        for (int di = 0; di < 6; ++di) o[mi][di][r] *= alpha;
      }

    // P: C-layout -> A-layout via per-wave LDS buffer, reused across mi
    // (same-wave DS ops complete in order -> no barrier needed between mi phases)
#pragma unroll
    for (int mi = 0; mi < 2; ++mi) {
#pragma unroll
      for (int ni = 0; ni < 4; ++ni)
#pragma unroll
        for (int r = 0; r < 4; ++r)
          sP[wave][(quad * 4 + r) * SP_STRIDE + ni * 16 + r16] = (_Float16)sacc[mi][ni][r];
#pragma unroll
      for (int kp = 0; kp < 2; ++kp) {
        half8 pf = *(const half8*)(&sP[wave][r16 * SP_STRIDE + kp * 32 + quad * 8]);
#pragma unroll
        for (int di = 0; di < 6; ++di) {
          half8 vf = *(const half8*)(sV + (di * 16 + r16) * SV_STRIDE + kp * 32 + quad * 8);
          o[mi][di] = __builtin_amdgcn_mfma_f32_16x16x32_f16(pf, vf, o[mi][di], 0, 0, 0);
        }
      }
    }
  }

  // epilogue: l = o[mi][5] col 80 lives in r16==0 lane of each 16-group
  const int b = bh >> 4, h = bh & 15;
#pragma unroll
  for (int mi = 0; mi < 2; ++mi)
#pragma unroll
    for (int r = 0; r < 4; ++r) {
      float l = __shfl(o[mi][5][r], lane & 48);
      float inv = 1.0f / l;
      int tok = b * SEQ + q0 + wave * 32 + mi * 16 + quad * 4 + r;
#pragma unroll
      for (int di = 0; di < 5; ++di) {
        int e = h * HD + di * 16 + r16;
        attn_out[(size_t)tok * EMBED + e] = (_Float16)(o[mi][di][r] * inv);
      }
    }
}

// ---------------- launch ----------------
extern "C" void kernel_launch(void* const* d_in, const int* in_sizes, int n_in,
                              void* d_out, int out_size, void* d_ws, size_t ws_size,
                              hipStream_t stream) {
  const float* hidden = (const float*)d_in[0];
  const float* w_qkv  = (const float*)d_in[1];
  const float* b_qkv  = (const float*)d_in[2];
  const float* w_proj = (const float*)d_in[3];
  const float* b_proj = (const float*)d_in[4];
  float* out = (float*)d_out;

  char* ws = (char*)d_ws;
  size_t off = 0;
  _Float16* hidden_h = (_Float16*)(ws + off); off += (size_t)MTOK * EMBED * 2;
  _Float16* wqkv_t   = (_Float16*)(ws + off); off += (size_t)NQKV * EMBED * 2;
  _Float16* wproj_t  = (_Float16*)(ws + off); off += (size_t)EMBED * EMBED * 2;
  _Float16* q_pad    = (_Float16*)(ws + off); off += (size_t)BATCH * NH * SEQ * HDP * 2;
  _Float16* k_pad    = (_Float16*)(ws + off); off += (size_t)BATCH * NH * SEQ * HDP * 2;
  _Float16* v_t      = (_Float16*)(ws + off); off += (size_t)BATCH * NH * HD * SEQ * 2;
  _Float16* attn_out = hidden_h;  // alias: hidden_h consumed before attention writes

  {
    int n4 = MTOK * EMBED / 4;
    cvt_f32_to_f16<<<(n4 + 255) / 256, 256, 0, stream>>>((const float4*)hidden, hidden_h, n4);
  }
  cvt_transpose_f16<NQKV><<<dim3(NQKV / 32, 1280 / 32), 256, 0, stream>>>(w_qkv, wqkv_t);
  cvt_transpose_f16<EMBED><<<dim3(EMBED / 32, 1280 / 32), 256, 0, stream>>>(w_proj, wproj_t);

  // QKV projection: M=16384, N=3840 -> 64 x 15 = 960 blocks (960 % 8 == 0)
  gemm256<0><<<960, 512, 0, stream>>>(hidden_h, wqkv_t, b_qkv, q_pad, k_pad, v_t, nullptr);

  attn_kernel<<<BATCH * NH * (SEQ / 128), 256, 0, stream>>>(q_pad, k_pad, v_t, attn_out);

  // output projection: M=16384, N=1280 -> 64 x 5 = 320 blocks (320 % 8 == 0)
  gemm256<1><<<320, 512, 0, stream>>>(attn_out, wproj_t, b_proj, nullptr, nullptr, nullptr, out);
}

// Round 3
// 627.121 us; speedup vs baseline: 1.0809x; 1.0370x over previous
//
#include <hip/hip_runtime.h>

// ---------------- problem constants ----------------
#define BATCH 16
#define SEQ   1024
#define EMBED 1280
#define NH    16
#define HD    80
#define HDP   96           // HD padded to 3*32 for MFMA K-steps
#define NQKV  3840
#define MTOK  (BATCH*SEQ)  // 16384
#define SCALE 0.11180339887498948f
#define LOG2E 1.4426950408889634f

// LDS strides padded to kill bank conflicts (keep 16B alignment for b128 reads)
#define SK_STRIDE 104      // 52 dwords
#define SV_STRIDE 72       // 36 dwords
#define SP_STRIDE 72

typedef _Float16 half8 __attribute__((ext_vector_type(8)));
typedef _Float16 half4 __attribute__((ext_vector_type(4)));
typedef float floatx4 __attribute__((ext_vector_type(4)));

#define GLD_TO_LDS(gp, lp)                                                        \
  __builtin_amdgcn_global_load_lds(                                               \
      (const __attribute__((address_space(1))) void*)(gp),                        \
      (__attribute__((address_space(3))) void*)(lp), 16, 0, 0)

// 16-lane all-reduce max on the VALU pipe (DPP)
__device__ __forceinline__ float rowmax16(float x) {
#define DPP_MAX(ctrl)                                                             \
  {                                                                               \
    float y = __int_as_float(                                                     \
        __builtin_amdgcn_update_dpp(0, __float_as_int(x), ctrl, 0xF, 0xF, true)); \
    x = fmaxf(x, y);                                                              \
  }
  DPP_MAX(0xB1);   // quad_perm [1,0,3,2]  (xor1)
  DPP_MAX(0x4E);   // quad_perm [2,3,0,1]  (xor2)
  DPP_MAX(0x141);  // row_half_mirror      (xor4 after uniform mod 4)
  DPP_MAX(0x140);  // row_mirror           (xor8 after uniform mod 8)
#undef DPP_MAX
  return x;
}

// ---------------- converts ----------------
__global__ void cvt_f32_to_f16(const float4* __restrict__ in, _Float16* __restrict__ out, int n4) {
  int i = blockIdx.x * blockDim.x + threadIdx.x;
  if (i < n4) {
    float4 v = in[i];
    half4 h;
    h[0] = (_Float16)v.x; h[1] = (_Float16)v.y; h[2] = (_Float16)v.z; h[3] = (_Float16)v.w;
    *(half4*)(out + (size_t)i * 4) = h;
  }
}

// in [K=1280 x N] fp32 row-major -> out [N x 1280] f16, LDS-tiled (coalesced both sides)
template <int N>
__global__ void cvt_transpose_f16(const float* __restrict__ in, _Float16* __restrict__ out) {
  __shared__ float tile[32][33];
  const int tx = threadIdx.x & 31, ty = threadIdx.x >> 5;  // 256 thr: ty 0..7
  const int k0 = blockIdx.y * 32;
  const int n0 = blockIdx.x * 32;
#pragma unroll
  for (int j = 0; j < 4; ++j)
    tile[ty + 8 * j][tx] = in[(size_t)(k0 + ty + 8 * j) * N + n0 + tx];
  __syncthreads();
#pragma unroll
  for (int j = 0; j < 4; ++j)
    out[(size_t)(n0 + ty + 8 * j) * 1280 + k0 + tx] = (_Float16)tile[tx][ty + 8 * j];
}

// ---------------- 256x256 GEMM, 4 phases/K-tile, ONE barrier per phase --------------------
// A [M x 1280] f16 row-major, Bt [N x 1280] f16 row-major (B transposed).
// 512 thr = 8 waves (2M x 4N); per-wave C = 128x64 as 8x4 16x16 frags.
// LDS: 2 dbuf x (256x64) x {A,B} f16 = 128 KiB. K = 1280 -> 20 K-tiles of BK=64.
// R2 change: dropped the pre-MFMA barrier + explicit lgkmcnt(0) of each quadrant.
// The compiler inserts fine-grained lgkmcnt(N) between ds_read and dependent MFMA
// (m97 asm evidence), so a wave enters MFMA as soon as its first frags are ready and
// waves desync within a phase -> DS reads overlap other waves' MFMAs.
// Hazard ledger (unchanged): every STAGE targets an LDS region whose readers drained
// before an END-of-phase barrier that precedes the STAGE's issue point:
//   q0 STAGE_A(1,T+1,D^1): other buffer, readers drained in GBODY(T-1)        -> safe
//   q2 STAGE_B(0,T+2,D):  sB[D] rows 0..127 read only in q0/q1 (wn=0,1)       -> safe
//   q3 STAGE_A(0,T+2,D):  sA[D] rows 0..127 read in q0/q2, drained by q2-bar  -> safe
//   q3 STAGE_B(1,T+2,D):  sB[D] rows 128..255 read q0/q1 (wn=2,3)             -> safe
// Publication: vmcnt(6) at end of GBODY(T-1) retires the 8 oldest loads = all of
// tile T; the end barrier makes them visible before GBODY(T) reads.

#define STAGE_A(H, T, D)                                                           \
  do {                                                                             \
    GLD_TO_LDS(aSrc0 + (size_t)((H) * 128) * 1280 + (T) * 64,                      \
               &sA[D][((H) * 128 + wave * 16) * 64]);                              \
    GLD_TO_LDS(aSrc0 + (size_t)((H) * 128 + 8) * 1280 + (T) * 64,                  \
               &sA[D][((H) * 128 + wave * 16 + 8) * 64]);                          \
  } while (0)

#define STAGE_B(H, T, D)                                                           \
  do {                                                                             \
    GLD_TO_LDS(bSrc0 + (size_t)((H) * 128) * 1280 + (T) * 64,                      \
               &sB[D][((H) * 128 + wave * 16) * 64]);                              \
    GLD_TO_LDS(bSrc0 + (size_t)((H) * 128 + 8) * 1280 + (T) * 64,                  \
               &sB[D][((H) * 128 + wave * 16 + 8) * 64]);                          \
  } while (0)

#define LDS_FRAG(P, ROWB, FR, KK) (*(const half8*)((P) + ((ROWB) + (FR) * 16) * 64 + cofs[KK]))

#define MFMA_Q(MIB, NIB)                                                           \
  _Pragma("unroll") for (int mi = 0; mi < 4; ++mi)                                 \
    _Pragma("unroll") for (int ni = 0; ni < 2; ++ni)                               \
      _Pragma("unroll") for (int kk = 0; kk < 2; ++kk)                             \
        acc[(MIB) + mi][(NIB) + ni] = __builtin_amdgcn_mfma_f32_16x16x32_f16(      \
            af[mi][kk], bf[(NIB) + ni][kk], acc[(MIB) + mi][(NIB) + ni], 0, 0, 0)

#define GBODY(T, D, S1, S2, VNSTR)                                                 \
  {                                                                                \
    const _Float16* pA = &sA[D][0];                                                \
    const _Float16* pB = &sB[D][0];                                                \
    /* ---- q0: frags A m0-3 + B n0-1; stage A-h1(T+1) ---- */                     \
    _Pragma("unroll") for (int mi = 0; mi < 4; ++mi)                               \
      _Pragma("unroll") for (int kk = 0; kk < 2; ++kk)                             \
        af[mi][kk] = LDS_FRAG(pA, rA, mi, kk);                                     \
    _Pragma("unroll") for (int ni = 0; ni < 2; ++ni)                               \
      _Pragma("unroll") for (int kk = 0; kk < 2; ++kk)                             \
        bf[ni][kk] = LDS_FRAG(pB, rB, ni, kk);                                     \
    if (S1) { STAGE_A(1, (T) + 1, (D) ^ 1); }                                      \
    __builtin_amdgcn_s_setprio(1);                                                 \
    MFMA_Q(0, 0);                                                                  \
    __builtin_amdgcn_s_setprio(0);                                                 \
    __builtin_amdgcn_s_barrier();                                                  \
    /* ---- q1: frags B n2-3 ---- */                                               \
    _Pragma("unroll") for (int ni = 0; ni < 2; ++ni)                               \
      _Pragma("unroll") for (int kk = 0; kk < 2; ++kk)                             \
        bf[2 + ni][kk] = LDS_FRAG(pB, rB, 2 + ni, kk);                             \
    __builtin_amdgcn_s_setprio(1);                                                 \
    MFMA_Q(0, 2);                                                                  \
    __builtin_amdgcn_s_setprio(0);                                                 \
    __builtin_amdgcn_s_barrier();                                                  \
    /* ---- q2: frags A m4-7; stage B-h0(T+2) ---- */                              \
    _Pragma("unroll") for (int mi = 0; mi < 4; ++mi)                               \
      _Pragma("unroll") for (int kk = 0; kk < 2; ++kk)                             \
        af[mi][kk] = LDS_FRAG(pA, rA, 4 + mi, kk);                                 \
    if (S2) { STAGE_B(0, (T) + 2, (D)); }                                          \
    __builtin_amdgcn_s_setprio(1);                                                 \
    MFMA_Q(4, 0);                                                                  \
    __builtin_amdgcn_s_setprio(0);                                                 \
    __builtin_amdgcn_s_barrier();                                                  \
    /* ---- q3: stage A-h0(T+2)+B-h1(T+2); MFMA; counted vmcnt ---- */             \
    if (S2) { STAGE_A(0, (T) + 2, (D)); STAGE_B(1, (T) + 2, (D)); }                \
    __builtin_amdgcn_s_setprio(1);                                                 \
    MFMA_Q(4, 2);                                                                  \
    __builtin_amdgcn_s_setprio(0);                                                 \
    asm volatile("s_waitcnt " VNSTR ::: "memory");                                 \
    __builtin_amdgcn_s_barrier();                                                  \
  }

template <int MODE>
__global__ __launch_bounds__(512, 2)
void gemm256(const _Float16* __restrict__ A, const _Float16* __restrict__ Bt,
             const float* __restrict__ bias,
             _Float16* __restrict__ q_pad, _Float16* __restrict__ k_pad,
             _Float16* __restrict__ v_t, float* __restrict__ outf) {
  __shared__ __align__(16) _Float16 sA[2][256 * 64];  // 64 KiB
  __shared__ __align__(16) _Float16 sB[2][256 * 64];  // 64 KiB

  const int tid = threadIdx.x;
  const int wave = tid >> 6, lane = tid & 63, quad = lane >> 4, r16 = lane & 15;
  const int wm = wave >> 2, wn = wave & 3;

  // XCD-contiguous swizzle: 64 m-tiles = 8 XCDs x 8; grid %% 8 == 0 for both MODEs.
  const int pid = blockIdx.x;
  const int xcd = pid & 7, local = pid >> 3;
  const int mt = xcd * 8 + (local & 7);
  const int nt = local >> 3;
  const int m0 = mt * 256, n0 = nt * 256;

  // staging source: row_local = wave*16 + i*8 + (lane>>3); chunk = (lane&7) ^ (lane>>3)
  const int l8 = lane >> 3, cg = (lane & 7) ^ l8;
  const _Float16* aSrc0 = A + ((size_t)m0 + wave * 16 + l8) * 1280 + cg * 8;
  const _Float16* bSrc0 = Bt + ((size_t)n0 + wave * 16 + l8) * 1280 + cg * 8;

  // fragment read bases (row&7 == r16&7 since frag rows are 16-aligned + r16)
  const int rA = wm * 128 + r16;
  const int rB = wn * 64 + r16;
  const int cofs[2] = { ((0 + quad) ^ (r16 & 7)) * 8, ((4 + quad) ^ (r16 & 7)) * 8 };

  floatx4 acc[8][4] = {};
  half8 af[4][2], bf[4][2];

  // prologue: tile0 full + tile1 (B-h0, A-h0, B-h1); A-h1(1) staged at (0,q0)
  STAGE_A(0, 0, 0); STAGE_A(1, 0, 0); STAGE_B(0, 0, 0); STAGE_B(1, 0, 0);
  STAGE_B(0, 1, 1); STAGE_A(0, 1, 1); STAGE_B(1, 1, 1);
  asm volatile("s_waitcnt vmcnt(6)" ::: "memory");  // tile0 landed; tile1 may be in flight
  __builtin_amdgcn_s_barrier();

  for (int it = 0; it < 9; ++it) {
    GBODY(2 * it, 0, true, true, "vmcnt(6)");
    GBODY(2 * it + 1, 1, true, true, "vmcnt(6)");
  }
  GBODY(18, 0, true, false, "vmcnt(0)");   // drain: A-h1(19) must land before t=19 reads
  GBODY(19, 1, false, false, "vmcnt(0)");

  // ---------------- epilogue ----------------
  if (MODE == 1) {
#pragma unroll
    for (int mi = 0; mi < 8; ++mi)
#pragma unroll
      for (int ni = 0; ni < 4; ++ni) {
        int n = n0 + wn * 64 + ni * 16 + r16;
        float bv = bias[n];
#pragma unroll
        for (int r = 0; r < 4; ++r) {
          int m = m0 + wm * 128 + mi * 16 + quad * 4 + r;
          outf[(size_t)m * EMBED + n] = acc[mi][ni][r] + bv;
        }
      }
  } else {
#pragma unroll
    for (int mi = 0; mi < 8; ++mi)
#pragma unroll
      for (int ni = 0; ni < 4; ++ni) {
        int n = n0 + wn * 64 + ni * 16 + r16;
        float bv = bias[n];
        int which = n / 1280;
        int rem = n - which * 1280;
        int h = rem / 80;
        int d = rem - h * 80;
#pragma unroll
        for (int r = 0; r < 4; ++r) {
          int m = m0 + wm * 128 + mi * 16 + quad * 4 + r;
          int b = m >> 10, s = m & 1023;
          int bh = b * NH + h;
          _Float16 val = (_Float16)(acc[mi][ni][r] + bv);
          if (which == 0) {
            q_pad[((size_t)bh * SEQ + s) * HDP + d] = val;
            if (d < 16) q_pad[((size_t)bh * SEQ + s) * HDP + 80 + d] = (_Float16)0.f;
          } else if (which == 1) {
            k_pad[((size_t)bh * SEQ + s) * HDP + d] = val;
            if (d < 16) k_pad[((size_t)bh * SEQ + s) * HDP + 80 + d] = (_Float16)0.f;
          } else {
            v_t[((size_t)bh * HD + d) * SEQ + s] = val;
          }
        }
      }
  }
}

// ---------------- flash attention (R2: dbuf K/V + async-stage split, 1 barrier/iter) ----
// grid: (BATCH*NH) * (SEQ/128) blocks, 256 thr. wave w owns q-rows [q0+w*32, +32) (mi=0,1).
// Per iter: issue 6 global loads for tile kt+1 -> QK^T on buf[cur] -> vmcnt + LDS-store
// into buf[cur^1] -> softmax -> PV -> single __syncthreads. HBM/L3 latency hides under
// QK^T (T14). WAR on buf[cur^1]: its readers (iter kt-1) drained before the end barrier
// of kt-1, and our stores are issued after it. LDS 63.2 KB -> 2 blocks/CU (as before).
__global__ __launch_bounds__(256, 2)
void attn_kernel(const _Float16* __restrict__ q_pad, const _Float16* __restrict__ k_pad,
                 const _Float16* __restrict__ v_t, _Float16* __restrict__ attn_out) {
  __shared__ __align__(16) _Float16 sK[2][64 * SK_STRIDE];   // 26.0 KB
  __shared__ __align__(16) _Float16 sV[2][96 * SV_STRIDE];   // 27.0 KB
  __shared__ __align__(16) _Float16 sP[4][16 * SP_STRIDE];   //  9.0 KB (reused mi=0 then mi=1)

  const int tid = threadIdx.x;
  const int wave = tid >> 6, lane = tid & 63, quad = lane >> 4, r16 = lane & 15;
  const int bh = blockIdx.x >> 3;
  const int q0 = (blockIdx.x & 7) * 128;

  // static sV rows 80..95 (ones row + zeros) in BOTH buffers; never overwritten in-loop
  if (tid < 128) {
    int row = 80 + (tid >> 3), col = (tid & 7) * 8;
    half8 z;
#pragma unroll
    for (int j = 0; j < 8; ++j) z[j] = (row == 80) ? (_Float16)1.f : (_Float16)0.f;
    *(half8*)(&sV[0][row * SV_STRIDE + col]) = z;
    *(half8*)(&sV[1][row * SV_STRIDE + col]) = z;
  }

  // Q fragments (A-layout), pre-scaled by SCALE*LOG2E (log2-domain softmax)
  half8 qf[2][3];
#pragma unroll
  for (int mi = 0; mi < 2; ++mi) {
    const _Float16* qb = q_pad + ((size_t)bh * SEQ + q0 + wave * 32 + mi * 16 + r16) * HDP;
#pragma unroll
    for (int kq = 0; kq < 3; ++kq) {
      half8 q = *(const half8*)(qb + kq * 32 + quad * 8);
#pragma unroll
      for (int j = 0; j < 8; ++j) q[j] = q[j] * (_Float16)(SCALE * LOG2E);
      qf[mi][kq] = q;
    }
  }

  // per-thread staging slots
  int rowK[3], colK[3];
#pragma unroll
  for (int i = 0; i < 3; ++i) {
    int c = tid + i * 256;
    rowK[i] = c / 12; colK[i] = c - rowK[i] * 12;
  }
  const int rowV0 = tid >> 3, colV0 = tid & 7;
  const _Float16* kgb = k_pad + ((size_t)bh * SEQ) * HDP;
  const _Float16* vgb = v_t + (size_t)bh * HD * SEQ;

  // prologue: stage tile 0 into buf 0
  {
    uint4 tk0 = *(const uint4*)(kgb + (size_t)(rowK[0]) * HDP + colK[0] * 8);
    uint4 tk1 = *(const uint4*)(kgb + (size_t)(rowK[1]) * HDP + colK[1] * 8);
    uint4 tk2 = *(const uint4*)(kgb + (size_t)(rowK[2]) * HDP + colK[2] * 8);
    uint4 tv0 = *(const uint4*)(vgb + (size_t)(rowV0) * SEQ + colV0 * 8);
    uint4 tv1 = *(const uint4*)(vgb + (size_t)(rowV0 + 32) * SEQ + colV0 * 8);
    *(uint4*)(&sK[0][rowK[0] * SK_STRIDE + colK[0] * 8]) = tk0;
    *(uint4*)(&sK[0][rowK[1] * SK_STRIDE + colK[1] * 8]) = tk1;
    *(uint4*)(&sK[0][rowK[2] * SK_STRIDE + colK[2] * 8]) = tk2;
    *(uint4*)(&sV[0][(rowV0)*SV_STRIDE + colV0 * 8]) = tv0;
    *(uint4*)(&sV[0][(rowV0 + 32) * SV_STRIDE + colV0 * 8]) = tv1;
    if (tid < 128) {
      uint4 tv2 = *(const uint4*)(vgb + (size_t)(rowV0 + 64) * SEQ + colV0 * 8);
      *(uint4*)(&sV[0][(rowV0 + 64) * SV_STRIDE + colV0 * 8]) = tv2;
    }
  }

  floatx4 o[2][6] = {};
  float mrow[2][4];
#pragma unroll
  for (int mi = 0; mi < 2; ++mi)
#pragma unroll
    for (int r = 0; r < 4; ++r) mrow[mi][r] = -1e30f;

  __syncthreads();  // tile0 + static rows visible

  for (int kt = 0; kt < 16; ++kt) {
    const int cur = kt & 1, nxt = cur ^ 1;

    // T14 issue-early: global loads for tile kt+1 (held in regs across QK^T)
    uint4 tk0, tk1, tk2, tv0, tv1, tv2;
    if (kt < 15) {
      const int kb = (kt + 1) * 64;
      tk0 = *(const uint4*)(kgb + (size_t)(kb + rowK[0]) * HDP + colK[0] * 8);
      tk1 = *(const uint4*)(kgb + (size_t)(kb + rowK[1]) * HDP + colK[1] * 8);
      tk2 = *(const uint4*)(kgb + (size_t)(kb + rowK[2]) * HDP + colK[2] * 8);
      tv0 = *(const uint4*)(vgb + (size_t)(rowV0)*SEQ + kb + colV0 * 8);
      tv1 = *(const uint4*)(vgb + (size_t)(rowV0 + 32) * SEQ + kb + colV0 * 8);
      if (tid < 128)
        tv2 = *(const uint4*)(vgb + (size_t)(rowV0 + 64) * SEQ + kb + colV0 * 8);
    }

    // S = Q K^T : 32 q-rows x 64 keys per wave (from sK[cur])
    floatx4 sacc[2][4] = {};
    __builtin_amdgcn_s_setprio(1);
#pragma unroll
    for (int ni = 0; ni < 4; ++ni)
#pragma unroll
      for (int kq = 0; kq < 3; ++kq) {
        half8 kf = *(const half8*)(&sK[cur][(ni * 16 + r16) * SK_STRIDE + kq * 32 + quad * 8]);
#pragma unroll
        for (int mi = 0; mi < 2; ++mi)
          sacc[mi][ni] = __builtin_amdgcn_mfma_f32_16x16x32_f16(qf[mi][kq], kf, sacc[mi][ni], 0, 0, 0);
      }
    __builtin_amdgcn_s_setprio(0);

    // write-late: publish tile kt+1 into the other buffer (vmcnt inserted by compiler)
    if (kt < 15) {
      *(uint4*)(&sK[nxt][rowK[0] * SK_STRIDE + colK[0] * 8]) = tk0;
      *(uint4*)(&sK[nxt][rowK[1] * SK_STRIDE + colK[1] * 8]) = tk1;
      *(uint4*)(&sK[nxt][rowK[2] * SK_STRIDE + colK[2] * 8]) = tk2;
      *(uint4*)(&sV[nxt][(rowV0)*SV_STRIDE + colV0 * 8]) = tv0;
      *(uint4*)(&sV[nxt][(rowV0 + 32) * SV_STRIDE + colV0 * 8]) = tv1;
      if (tid < 128)
        *(uint4*)(&sV[nxt][(rowV0 + 64) * SV_STRIDE + colV0 * 8]) = tv2;
    }

    // online softmax (log2 domain); sums via ones-row MFMA, max via DPP
#pragma unroll
    for (int mi = 0; mi < 2; ++mi)
#pragma unroll
      for (int r = 0; r < 4; ++r) {
        float mx = fmaxf(fmaxf(sacc[mi][0][r], sacc[mi][1][r]),
                         fmaxf(sacc[mi][2][r], sacc[mi][3][r]));
        mx = rowmax16(mx);
        float mnew = fmaxf(mrow[mi][r], mx);
        float alpha = __builtin_amdgcn_exp2f(mrow[mi][r] - mnew);
        mrow[mi][r] = mnew;
#pragma unroll
        for (int ni = 0; ni < 4; ++ni)
          sacc[mi][ni][r] = __builtin_amdgcn_exp2f(sacc[mi][ni][r] - mnew);
#pragma unroll
        for (int di = 0; di < 6; ++di) o[mi][di][r] *= alpha;
      }

    // P: C-layout -> A-layout via per-wave LDS buffer, reused across mi
    // (same-wave DS ops complete in order -> no barrier needed between mi phases)
#pragma unroll
    for (int mi = 0; mi < 2; ++mi) {
#pragma unroll
      for (int ni = 0; ni < 4; ++ni)
#pragma unroll
        for (int r = 0; r < 4; ++r)
          sP[wave][(quad * 4 + r) * SP_STRIDE + ni * 16 + r16] = (_Float16)sacc[mi][ni][r];
#pragma unroll
      for (int kp = 0; kp < 2; ++kp) {
        half8 pf = *(const half8*)(&sP[wave][r16 * SP_STRIDE + kp * 32 + quad * 8]);
        __builtin_amdgcn_s_setprio(1);
#pragma unroll
        for (int di = 0; di < 6; ++di) {
          half8 vf = *(const half8*)(&sV[cur][(di * 16 + r16) * SV_STRIDE + kp * 32 + quad * 8]);
          o[mi][di] = __builtin_amdgcn_mfma_f32_16x16x32_f16(pf, vf, o[mi][di], 0, 0, 0);
        }
        __builtin_amdgcn_s_setprio(0);
      }
    }

    __syncthreads();  // buf[cur] free for kt+2's stage; buf[nxt] published
  }

  // epilogue: l = o[mi][5] col 80 lives in r16==0 lane of each 16-group
  const int b = bh >> 4, h = bh & 15;
#pragma unroll
  for (int mi = 0; mi < 2; ++mi)
#pragma unroll
    for (int r = 0; r < 4; ++r) {
      float l = __shfl(o[mi][5][r], lane & 48);
      float inv = 1.0f / l;
      int tok = b * SEQ + q0 + wave * 32 + mi * 16 + quad * 4 + r;
#pragma unroll
      for (int di = 0; di < 5; ++di) {
        int e = h * HD + di * 16 + r16;
        attn_out[(size_t)tok * EMBED + e] = (_Float16)(o[mi][di][r] * inv);
      }
    }
}

// ---------------- launch ----------------
extern "C" void kernel_launch(void* const* d_in, const int* in_sizes, int n_in,
                              void* d_out, int out_size, void* d_ws, size_t ws_size,
                              hipStream_t stream) {
  const float* hidden = (const float*)d_in[0];
  const float* w_qkv  = (const float*)d_in[1];
  const float* b_qkv  = (const float*)d_in[2];
  const float* w_proj = (const float*)d_in[3];
  const float* b_proj = (const float*)d_in[4];
  float* out = (float*)d_out;

  char* ws = (char*)d_ws;
  size_t off = 0;
  _Float16* hidden_h = (_Float16*)(ws + off); off += (size_t)MTOK * EMBED * 2;
  _Float16* wqkv_t   = (_Float16*)(ws + off); off += (size_t)NQKV * EMBED * 2;
  _Float16* wproj_t  = (_Float16*)(ws + off); off += (size_t)EMBED * EMBED * 2;
  _Float16* q_pad    = (_Float16*)(ws + off); off += (size_t)BATCH * NH * SEQ * HDP * 2;
  _Float16* k_pad    = (_Float16*)(ws + off); off += (size_t)BATCH * NH * SEQ * HDP * 2;
  _Float16* v_t      = (_Float16*)(ws + off); off += (size_t)BATCH * NH * HD * SEQ * 2;
  _Float16* attn_out = hidden_h;  // alias: hidden_h consumed before attention writes

  {
    int n4 = MTOK * EMBED / 4;
    cvt_f32_to_f16<<<(n4 + 255) / 256, 256, 0, stream>>>((const float4*)hidden, hidden_h, n4);
  }
  cvt_transpose_f16<NQKV><<<dim3(NQKV / 32, 1280 / 32), 256, 0, stream>>>(w_qkv, wqkv_t);
  cvt_transpose_f16<EMBED><<<dim3(EMBED / 32, 1280 / 32), 256, 0, stream>>>(w_proj, wproj_t);

  // QKV projection: M=16384, N=3840 -> 64 x 15 = 960 blocks (960 % 8 == 0)
  gemm256<0><<<960, 512, 0, stream>>>(hidden_h, wqkv_t, b_qkv, q_pad, k_pad, v_t, nullptr);

  attn_kernel<<<BATCH * NH * (SEQ / 128), 256, 0, stream>>>(q_pad, k_pad, v_t, attn_out);

  // output projection: M=16384, N=1280 -> 64 x 5 = 320 blocks (320 % 8 == 0)
  gemm256<1><<<320, 512, 0, stream>>>(attn_out, wproj_t, b_proj, nullptr, nullptr, nullptr, out);
}

// Round 4
// 596.125 us; speedup vs baseline: 1.1371x; 1.0520x over previous
//
#include <hip/hip_runtime.h>

// ---------------- problem constants ----------------
#define BATCH 16
#define SEQ   1024
#define EMBED 1280
#define NH    16
#define HD    80
#define HDP   96           // HD padded to 3*32 for MFMA K-steps
#define NQKV  3840
#define MTOK  (BATCH*SEQ)  // 16384
#define SCALE 0.11180339887498948f
#define LOG2E 1.4426950408889634f

// LDS strides padded to kill bank conflicts (keep 16B alignment for b128 reads)
#define SK_STRIDE 104      // 52 dwords
#define SV_STRIDE 72       // 36 dwords
#define SP_STRIDE 72

typedef _Float16 half8 __attribute__((ext_vector_type(8)));
typedef _Float16 half4 __attribute__((ext_vector_type(4)));
typedef float floatx4 __attribute__((ext_vector_type(4)));

#define GLD_TO_LDS(gp, lp)                                                        \
  __builtin_amdgcn_global_load_lds(                                               \
      (const __attribute__((address_space(1))) void*)(gp),                        \
      (__attribute__((address_space(3))) void*)(lp), 16, 0, 0)

// 16-lane all-reduce max on the VALU pipe (DPP)
__device__ __forceinline__ float rowmax16(float x) {
#define DPP_MAX(ctrl)                                                             \
  {                                                                               \
    float y = __int_as_float(                                                     \
        __builtin_amdgcn_update_dpp(0, __float_as_int(x), ctrl, 0xF, 0xF, true)); \
    x = fmaxf(x, y);                                                              \
  }
  DPP_MAX(0xB1);   // quad_perm [1,0,3,2]  (xor1)
  DPP_MAX(0x4E);   // quad_perm [2,3,0,1]  (xor2)
  DPP_MAX(0x141);  // row_half_mirror      (xor4 after uniform mod 4)
  DPP_MAX(0x140);  // row_mirror           (xor8 after uniform mod 8)
#undef DPP_MAX
  return x;
}

// ---------------- converts ----------------
__global__ void cvt_f32_to_f16(const float4* __restrict__ in, _Float16* __restrict__ out, int n4) {
  int i = blockIdx.x * blockDim.x + threadIdx.x;
  if (i < n4) {
    float4 v = in[i];
    half4 h;
    h[0] = (_Float16)v.x; h[1] = (_Float16)v.y; h[2] = (_Float16)v.z; h[3] = (_Float16)v.w;
    *(half4*)(out + (size_t)i * 4) = h;
  }
}

// in [K=1280 x N] fp32 row-major -> out [N x 1280] f16, LDS-tiled (coalesced both sides)
template <int N>
__global__ void cvt_transpose_f16(const float* __restrict__ in, _Float16* __restrict__ out) {
  __shared__ float tile[32][33];
  const int tx = threadIdx.x & 31, ty = threadIdx.x >> 5;  // 256 thr: ty 0..7
  const int k0 = blockIdx.y * 32;
  const int n0 = blockIdx.x * 32;
#pragma unroll
  for (int j = 0; j < 4; ++j)
    tile[ty + 8 * j][tx] = in[(size_t)(k0 + ty + 8 * j) * N + n0 + tx];
  __syncthreads();
#pragma unroll
  for (int j = 0; j < 4; ++j)
    out[(size_t)(n0 + ty + 8 * j) * 1280 + k0 + tx] = (_Float16)tile[tx][ty + 8 * j];
}

// ---------------- 256x256 GEMM, 2 barriers/K-tile, wave-internal ds_read<->MFMA overlap ----
// A [M x 1280] f16 row-major, Bt [N x 1280] f16 row-major (B transposed).
// 512 thr = 8 waves (2M x 4N); per-wave C = 128x64 as 8x4 16x16 frags.
// LDS: 2 dbuf x (256x64) x {A,B} f16 = 128 KiB. K = 1280 -> 20 K-tiles of BK=64.
// R4 theory: phase-lockstep serialized LDS-read time against the (per-CU) MFMA pipe.
// New tile shape: burst-read af(m0-3)+bf(all) -> 32 MFMA (compiler's fine lgkmcnt lets
// MFMAs start while the read tail drains) -> re-read af(m4-7) under MFMA tail ->
// mid-barrier -> stage B(T+2) -> 32 MFMA -> vmcnt(4) -> final barrier.
// Hazard ledger:
//  early STAGE_A(*,T+1,D^1): tile T-1 (buf D^1) readers retired before its final
//    barrier (its half2 MFMAs consumed them) -> WAR-safe at tile T start.
//  mid STAGE_B(*,T+2,D): all bf reads of sB[D] consumed by half-1 MFMAs before the
//    mid barrier in every wave -> safe. af(m4-7) reads target sA only -> no overlap.
//  Publication: vmcnt(4) at tile T end retires [B(T+1) from T-1 mid] + [A(T+1) from
//    T early], leaving exactly the 4 B(T+2) loads in flight; final barrier publishes.
//  Tail: tile 18 drains vmcnt(0) (A(19)+B(19) landed); tile 19 stages nothing.

#define STAGE_A(H, T, D)                                                           \
  do {                                                                             \
    GLD_TO_LDS(aSrc0 + (size_t)((H) * 128) * 1280 + (T) * 64,                      \
               &sA[D][((H) * 128 + wave * 16) * 64]);                              \
    GLD_TO_LDS(aSrc0 + (size_t)((H) * 128 + 8) * 1280 + (T) * 64,                  \
               &sA[D][((H) * 128 + wave * 16 + 8) * 64]);                          \
  } while (0)

#define STAGE_B(H, T, D)                                                           \
  do {                                                                             \
    GLD_TO_LDS(bSrc0 + (size_t)((H) * 128) * 1280 + (T) * 64,                      \
               &sB[D][((H) * 128 + wave * 16) * 64]);                              \
    GLD_TO_LDS(bSrc0 + (size_t)((H) * 128 + 8) * 1280 + (T) * 64,                  \
               &sB[D][((H) * 128 + wave * 16 + 8) * 64]);                          \
  } while (0)

#define LDS_FRAG(P, ROWB, FR, KK) (*(const half8*)((P) + ((ROWB) + (FR) * 16) * 64 + cofs[KK]))

#define MFMA_Q(MIB, NIB)                                                           \
  _Pragma("unroll") for (int mi = 0; mi < 4; ++mi)                                 \
    _Pragma("unroll") for (int ni = 0; ni < 2; ++ni)                               \
      _Pragma("unroll") for (int kk = 0; kk < 2; ++kk)                             \
        acc[(MIB) + mi][(NIB) + ni] = __builtin_amdgcn_mfma_f32_16x16x32_f16(      \
            af[mi][kk], bf[(NIB) + ni][kk], acc[(MIB) + mi][(NIB) + ni], 0, 0, 0)

#define GBODY2(T, D, SA, SB, VNSTR)                                                \
  {                                                                                \
    const _Float16* pA = &sA[D][0];                                                \
    const _Float16* pB = &sB[D][0];                                                \
    if (SA) { STAGE_A(0, (T) + 1, (D) ^ 1); STAGE_A(1, (T) + 1, (D) ^ 1); }        \
    _Pragma("unroll") for (int mi = 0; mi < 4; ++mi)                               \
      _Pragma("unroll") for (int kk = 0; kk < 2; ++kk)                             \
        af[mi][kk] = LDS_FRAG(pA, rA, mi, kk);                                     \
    _Pragma("unroll") for (int ni = 0; ni < 4; ++ni)                               \
      _Pragma("unroll") for (int kk = 0; kk < 2; ++kk)                             \
        bf[ni][kk] = LDS_FRAG(pB, rB, ni, kk);                                     \
    __builtin_amdgcn_s_setprio(1);                                                 \
    MFMA_Q(0, 0);                                                                  \
    MFMA_Q(0, 2);                                                                  \
    __builtin_amdgcn_s_setprio(0);                                                 \
    _Pragma("unroll") for (int mi = 0; mi < 4; ++mi)                               \
      _Pragma("unroll") for (int kk = 0; kk < 2; ++kk)                             \
        af[mi][kk] = LDS_FRAG(pA, rA, 4 + mi, kk);                                 \
    __builtin_amdgcn_s_barrier();                                                  \
    if (SB) { STAGE_B(0, (T) + 2, (D)); STAGE_B(1, (T) + 2, (D)); }                \
    __builtin_amdgcn_s_setprio(1);                                                 \
    MFMA_Q(4, 0);                                                                  \
    MFMA_Q(4, 2);                                                                  \
    __builtin_amdgcn_s_setprio(0);                                                 \
    asm volatile("s_waitcnt " VNSTR ::: "memory");                                 \
    __builtin_amdgcn_s_barrier();                                                  \
  }

template <int MODE>
__global__ __launch_bounds__(512, 2)
void gemm256(const _Float16* __restrict__ A, const _Float16* __restrict__ Bt,
             const float* __restrict__ bias,
             _Float16* __restrict__ q_pad, _Float16* __restrict__ k_pad,
             _Float16* __restrict__ v_t, float* __restrict__ outf) {
  __shared__ __align__(16) _Float16 sA[2][256 * 64];  // 64 KiB
  __shared__ __align__(16) _Float16 sB[2][256 * 64];  // 64 KiB

  const int tid = threadIdx.x;
  const int wave = tid >> 6, lane = tid & 63, quad = lane >> 4, r16 = lane & 15;
  const int wm = wave >> 2, wn = wave & 3;

  // XCD-contiguous swizzle: 64 m-tiles = 8 XCDs x 8; grid %% 8 == 0 for both MODEs.
  const int pid = blockIdx.x;
  const int xcd = pid & 7, local = pid >> 3;
  const int mt = xcd * 8 + (local & 7);
  const int nt = local >> 3;
  const int m0 = mt * 256, n0 = nt * 256;

  // staging source: row_local = wave*16 + i*8 + (lane>>3); chunk = (lane&7) ^ (lane>>3)
  const int l8 = lane >> 3, cg = (lane & 7) ^ l8;
  const _Float16* aSrc0 = A + ((size_t)m0 + wave * 16 + l8) * 1280 + cg * 8;
  const _Float16* bSrc0 = Bt + ((size_t)n0 + wave * 16 + l8) * 1280 + cg * 8;

  // fragment read bases (row&7 == r16&7 since frag rows are 16-aligned + r16)
  const int rA = wm * 128 + r16;
  const int rB = wn * 64 + r16;
  const int cofs[2] = { ((0 + quad) ^ (r16 & 7)) * 8, ((4 + quad) ^ (r16 & 7)) * 8 };

  floatx4 acc[8][4] = {};
  half8 af[4][2], bf[4][2];

  // prologue: tile0 full + B(1); A(1) is staged in tile0's early slot
  STAGE_A(0, 0, 0); STAGE_A(1, 0, 0); STAGE_B(0, 0, 0); STAGE_B(1, 0, 0);
  STAGE_B(0, 1, 1); STAGE_B(1, 1, 1);
  asm volatile("s_waitcnt vmcnt(4)" ::: "memory");  // tile0 landed; B(1) may be in flight
  __builtin_amdgcn_s_barrier();

  for (int it = 0; it < 9; ++it) {
    GBODY2(2 * it, 0, true, true, "vmcnt(4)");
    GBODY2(2 * it + 1, 1, true, true, "vmcnt(4)");
  }
  GBODY2(18, 0, true, false, "vmcnt(0)");   // drain: A(19)+B(19) must land
  GBODY2(19, 1, false, false, "vmcnt(0)");

  // ---------------- epilogue ----------------
  if (MODE == 1) {
#pragma unroll
    for (int mi = 0; mi < 8; ++mi)
#pragma unroll
      for (int ni = 0; ni < 4; ++ni) {
        int n = n0 + wn * 64 + ni * 16 + r16;
        float bv = bias[n];
#pragma unroll
        for (int r = 0; r < 4; ++r) {
          int m = m0 + wm * 128 + mi * 16 + quad * 4 + r;
          outf[(size_t)m * EMBED + n] = acc[mi][ni][r] + bv;
        }
      }
  } else {
#pragma unroll
    for (int mi = 0; mi < 8; ++mi)
#pragma unroll
      for (int ni = 0; ni < 4; ++ni) {
        int n = n0 + wn * 64 + ni * 16 + r16;
        float bv = bias[n];
        int which = n / 1280;
        int rem = n - which * 1280;
        int h = rem / 80;
        int d = rem - h * 80;
        int mbase = m0 + wm * 128 + mi * 16 + quad * 4;  // 4-aligned, never crosses SEQ
        int b = mbase >> 10, s = mbase & 1023;
        int bh = b * NH + h;
        if (which == 2) {
          // v_t[bh][d][s]: 4 consecutive s per lane -> one 8B store (was 4x 2B scatter)
          half4 pv;
#pragma unroll
          for (int r = 0; r < 4; ++r) pv[r] = (_Float16)(acc[mi][ni][r] + bv);
          *(half4*)(v_t + ((size_t)bh * HD + d) * SEQ + s) = pv;
        } else {
          _Float16* dst = (which == 0) ? q_pad : k_pad;
#pragma unroll
          for (int r = 0; r < 4; ++r) {
            _Float16 val = (_Float16)(acc[mi][ni][r] + bv);
            dst[((size_t)bh * SEQ + (s + r)) * HDP + d] = val;
            if (d < 16) dst[((size_t)bh * SEQ + (s + r)) * HDP + 80 + d] = (_Float16)0.f;
          }
        }
      }
  }
}

// ---------------- flash attention (dbuf K/V + async-stage split, 1 barrier/iter) ----
// grid: (BATCH*NH) * (SEQ/128) blocks, 256 thr. wave w owns q-rows [q0+w*32, +32) (mi=0,1).
// Per iter: issue 6 global loads for tile kt+1 -> QK^T on buf[cur] -> vmcnt + LDS-store
// into buf[cur^1] -> softmax -> PV -> single __syncthreads. HBM/L3 latency hides under
// QK^T (T14). WAR on buf[cur^1]: its readers (iter kt-1) drained before the end barrier
// of kt-1, and our stores are issued after it. LDS 63.2 KB -> 2 blocks/CU.
__global__ __launch_bounds__(256, 2)
void attn_kernel(const _Float16* __restrict__ q_pad, const _Float16* __restrict__ k_pad,
                 const _Float16* __restrict__ v_t, _Float16* __restrict__ attn_out) {
  __shared__ __align__(16) _Float16 sK[2][64 * SK_STRIDE];   // 26.0 KB
  __shared__ __align__(16) _Float16 sV[2][96 * SV_STRIDE];   // 27.0 KB
  __shared__ __align__(16) _Float16 sP[4][16 * SP_STRIDE];   //  9.0 KB (reused mi=0 then mi=1)

  const int tid = threadIdx.x;
  const int wave = tid >> 6, lane = tid & 63, quad = lane >> 4, r16 = lane & 15;
  const int bh = blockIdx.x >> 3;
  const int q0 = (blockIdx.x & 7) * 128;

  // static sV rows 80..95 (ones row + zeros) in BOTH buffers; never overwritten in-loop
  if (tid < 128) {
    int row = 80 + (tid >> 3), col = (tid & 7) * 8;
    half8 z;
#pragma unroll
    for (int j = 0; j < 8; ++j) z[j] = (row == 80) ? (_Float16)1.f : (_Float16)0.f;
    *(half8*)(&sV[0][row * SV_STRIDE + col]) = z;
    *(half8*)(&sV[1][row * SV_STRIDE + col]) = z;
  }

  // Q fragments (A-layout), pre-scaled by SCALE*LOG2E (log2-domain softmax)
  half8 qf[2][3];
#pragma unroll
  for (int mi = 0; mi < 2; ++mi) {
    const _Float16* qb = q_pad + ((size_t)bh * SEQ + q0 + wave * 32 + mi * 16 + r16) * HDP;
#pragma unroll
    for (int kq = 0; kq < 3; ++kq) {
      half8 q = *(const half8*)(qb + kq * 32 + quad * 8);
#pragma unroll
      for (int j = 0; j < 8; ++j) q[j] = q[j] * (_Float16)(SCALE * LOG2E);
      qf[mi][kq] = q;
    }
  }

  // per-thread staging slots
  int rowK[3], colK[3];
#pragma unroll
  for (int i = 0; i < 3; ++i) {
    int c = tid + i * 256;
    rowK[i] = c / 12; colK[i] = c - rowK[i] * 12;
  }
  const int rowV0 = tid >> 3, colV0 = tid & 7;
  const _Float16* kgb = k_pad + ((size_t)bh * SEQ) * HDP;
  const _Float16* vgb = v_t + (size_t)bh * HD * SEQ;

  // prologue: stage tile 0 into buf 0
  {
    uint4 tk0 = *(const uint4*)(kgb + (size_t)(rowK[0]) * HDP + colK[0] * 8);
    uint4 tk1 = *(const uint4*)(kgb + (size_t)(rowK[1]) * HDP + colK[1] * 8);
    uint4 tk2 = *(const uint4*)(kgb + (size_t)(rowK[2]) * HDP + colK[2] * 8);
    uint4 tv0 = *(const uint4*)(vgb + (size_t)(rowV0) * SEQ + colV0 * 8);
    uint4 tv1 = *(const uint4*)(vgb + (size_t)(rowV0 + 32) * SEQ + colV0 * 8);
    *(uint4*)(&sK[0][rowK[0] * SK_STRIDE + colK[0] * 8]) = tk0;
    *(uint4*)(&sK[0][rowK[1] * SK_STRIDE + colK[1] * 8]) = tk1;
    *(uint4*)(&sK[0][rowK[2] * SK_STRIDE + colK[2] * 8]) = tk2;
    *(uint4*)(&sV[0][(rowV0)*SV_STRIDE + colV0 * 8]) = tv0;
    *(uint4*)(&sV[0][(rowV0 + 32) * SV_STRIDE + colV0 * 8]) = tv1;
    if (tid < 128) {
      uint4 tv2 = *(const uint4*)(vgb + (size_t)(rowV0 + 64) * SEQ + colV0 * 8);
      *(uint4*)(&sV[0][(rowV0 + 64) * SV_STRIDE + colV0 * 8]) = tv2;
    }
  }

  floatx4 o[2][6] = {};
  float mrow[2][4];
#pragma unroll
  for (int mi = 0; mi < 2; ++mi)
#pragma unroll
    for (int r = 0; r < 4; ++r) mrow[mi][r] = -1e30f;

  __syncthreads();  // tile0 + static rows visible

  for (int kt = 0; kt < 16; ++kt) {
    const int cur = kt & 1, nxt = cur ^ 1;

    // T14 issue-early: global loads for tile kt+1 (held in regs across QK^T)
    uint4 tk0, tk1, tk2, tv0, tv1, tv2;
    if (kt < 15) {
      const int kb = (kt + 1) * 64;
      tk0 = *(const uint4*)(kgb + (size_t)(kb + rowK[0]) * HDP + colK[0] * 8);
      tk1 = *(const uint4*)(kgb + (size_t)(kb + rowK[1]) * HDP + colK[1] * 8);
      tk2 = *(const uint4*)(kgb + (size_t)(kb + rowK[2]) * HDP + colK[2] * 8);
      tv0 = *(const uint4*)(vgb + (size_t)(rowV0)*SEQ + kb + colV0 * 8);
      tv1 = *(const uint4*)(vgb + (size_t)(rowV0 + 32) * SEQ + kb + colV0 * 8);
      if (tid < 128)
        tv2 = *(const uint4*)(vgb + (size_t)(rowV0 + 64) * SEQ + kb + colV0 * 8);
    }

    // S = Q K^T : 32 q-rows x 64 keys per wave (from sK[cur])
    floatx4 sacc[2][4] = {};
    __builtin_amdgcn_s_setprio(1);
#pragma unroll
    for (int ni = 0; ni < 4; ++ni)
#pragma unroll
      for (int kq = 0; kq < 3; ++kq) {
        half8 kf = *(const half8*)(&sK[cur][(ni * 16 + r16) * SK_STRIDE + kq * 32 + quad * 8]);
#pragma unroll
        for (int mi = 0; mi < 2; ++mi)
          sacc[mi][ni] = __builtin_amdgcn_mfma_f32_16x16x32_f16(qf[mi][kq], kf, sacc[mi][ni], 0, 0, 0);
      }
    __builtin_amdgcn_s_setprio(0);

    // write-late: publish tile kt+1 into the other buffer (vmcnt inserted by compiler)
    if (kt < 15) {
      *(uint4*)(&sK[nxt][rowK[0] * SK_STRIDE + colK[0] * 8]) = tk0;
      *(uint4*)(&sK[nxt][rowK[1] * SK_STRIDE + colK[1] * 8]) = tk1;
      *(uint4*)(&sK[nxt][rowK[2] * SK_STRIDE + colK[2] * 8]) = tk2;
      *(uint4*)(&sV[nxt][(rowV0)*SV_STRIDE + colV0 * 8]) = tv0;
      *(uint4*)(&sV[nxt][(rowV0 + 32) * SV_STRIDE + colV0 * 8]) = tv1;
      if (tid < 128)
        *(uint4*)(&sV[nxt][(rowV0 + 64) * SV_STRIDE + colV0 * 8]) = tv2;
    }

    // online softmax (log2 domain); sums via ones-row MFMA, max via DPP
#pragma unroll
    for (int mi = 0; mi < 2; ++mi)
#pragma unroll
      for (int r = 0; r < 4; ++r) {
        float mx = fmaxf(fmaxf(sacc[mi][0][r], sacc[mi][1][r]),
                         fmaxf(sacc[mi][2][r], sacc[mi][3][r]));
        mx = rowmax16(mx);
        float mnew = fmaxf(mrow[mi][r], mx);
        float alpha = __builtin_amdgcn_exp2f(mrow[mi][r] - mnew);
        mrow[mi][r] = mnew;
#pragma unroll
        for (int ni = 0; ni < 4; ++ni)
          sacc[mi][ni][r] = __builtin_amdgcn_exp2f(sacc[mi][ni][r] - mnew);
#pragma unroll
        for (int di = 0; di < 6; ++di) o[mi][di][r] *= alpha;
      }

    // P: C-layout -> A-layout via per-wave LDS buffer, reused across mi
    // (same-wave DS ops complete in order -> no barrier needed between mi phases)
#pragma unroll
    for (int mi = 0; mi < 2; ++mi) {
#pragma unroll
      for (int ni = 0; ni < 4; ++ni)
#pragma unroll
        for (int r = 0; r < 4; ++r)
          sP[wave][(quad * 4 + r) * SP_STRIDE + ni * 16 + r16] = (_Float16)sacc[mi][ni][r];
#pragma unroll
      for (int kp = 0; kp < 2; ++kp) {
        half8 pf = *(const half8*)(&sP[wave][r16 * SP_STRIDE + kp * 32 + quad * 8]);
        __builtin_amdgcn_s_setprio(1);
#pragma unroll
        for (int di = 0; di < 6; ++di) {
          half8 vf = *(const half8*)(&sV[cur][(di * 16 + r16) * SV_STRIDE + kp * 32 + quad * 8]);
          o[mi][di] = __builtin_amdgcn_mfma_f32_16x16x32_f16(pf, vf, o[mi][di], 0, 0, 0);
        }
        __builtin_amdgcn_s_setprio(0);
      }
    }

    __syncthreads();  // buf[cur] free for kt+2's stage; buf[nxt] published
  }

  // epilogue: l = o[mi][5] col 80 lives in r16==0 lane of each 16-group
  const int b = bh >> 4, h = bh & 15;
#pragma unroll
  for (int mi = 0; mi < 2; ++mi)
#pragma unroll
    for (int r = 0; r < 4; ++r) {
      float l = __shfl(o[mi][5][r], lane & 48);
      float inv = 1.0f / l;
      int tok = b * SEQ + q0 + wave * 32 + mi * 16 + quad * 4 + r;
#pragma unroll
      for (int di = 0; di < 5; ++di) {
        int e = h * HD + di * 16 + r16;
        attn_out[(size_t)tok * EMBED + e] = (_Float16)(o[mi][di][r] * inv);
      }
    }
}

// ---------------- launch ----------------
extern "C" void kernel_launch(void* const* d_in, const int* in_sizes, int n_in,
                              void* d_out, int out_size, void* d_ws, size_t ws_size,
                              hipStream_t stream) {
  const float* hidden = (const float*)d_in[0];
  const float* w_qkv  = (const float*)d_in[1];
  const float* b_qkv  = (const float*)d_in[2];
  const float* w_proj = (const float*)d_in[3];
  const float* b_proj = (const float*)d_in[4];
  float* out = (float*)d_out;

  char* ws = (char*)d_ws;
  size_t off = 0;
  _Float16* hidden_h = (_Float16*)(ws + off); off += (size_t)MTOK * EMBED * 2;
  _Float16* wqkv_t   = (_Float16*)(ws + off); off += (size_t)NQKV * EMBED * 2;
  _Float16* wproj_t  = (_Float16*)(ws + off); off += (size_t)EMBED * EMBED * 2;
  _Float16* q_pad    = (_Float16*)(ws + off); off += (size_t)BATCH * NH * SEQ * HDP * 2;
  _Float16* k_pad    = (_Float16*)(ws + off); off += (size_t)BATCH * NH * SEQ * HDP * 2;
  _Float16* v_t      = (_Float16*)(ws + off); off += (size_t)BATCH * NH * HD * SEQ * 2;
  _Float16* attn_out = hidden_h;  // alias: hidden_h consumed before attention writes

  {
    int n4 = MTOK * EMBED / 4;
    cvt_f32_to_f16<<<(n4 + 255) / 256, 256, 0, stream>>>((const float4*)hidden, hidden_h, n4);
  }
  cvt_transpose_f16<NQKV><<<dim3(NQKV / 32, 1280 / 32), 256, 0, stream>>>(w_qkv, wqkv_t);
  cvt_transpose_f16<EMBED><<<dim3(EMBED / 32, 1280 / 32), 256, 0, stream>>>(w_proj, wproj_t);

  // QKV projection: M=16384, N=3840 -> 64 x 15 = 960 blocks (960 % 8 == 0)
  gemm256<0><<<960, 512, 0, stream>>>(hidden_h, wqkv_t, b_qkv, q_pad, k_pad, v_t, nullptr);

  attn_kernel<<<BATCH * NH * (SEQ / 128), 256, 0, stream>>>(q_pad, k_pad, v_t, attn_out);

  // output projection: M=16384, N=1280 -> 64 x 5 = 320 blocks (320 % 8 == 0)
  gemm256<1><<<320, 512, 0, stream>>>(attn_out, wproj_t, b_proj, nullptr, nullptr, nullptr, out);
}

// Round 5
// 585.085 us; speedup vs baseline: 1.1585x; 1.0189x over previous
//
#include <hip/hip_runtime.h>

// ---------------- problem constants ----------------
#define BATCH 16
#define SEQ   1024
#define EMBED 1280
#define NH    16
#define HD    80
#define HDP   96           // HD padded to 3*32 for MFMA K-steps
#define NQKV  3840
#define MTOK  (BATCH*SEQ)  // 16384
#define SCALE 0.11180339887498948f
#define LOG2E 1.4426950408889634f

// LDS strides padded to kill bank conflicts (keep 16B alignment for b128 reads)
#define SK_STRIDE 104      // 52 dwords
#define SV_STRIDE 72       // 36 dwords
#define SP_STRIDE 72

typedef _Float16 half8 __attribute__((ext_vector_type(8)));
typedef _Float16 half4 __attribute__((ext_vector_type(4)));
typedef float floatx4 __attribute__((ext_vector_type(4)));

#define GLD_TO_LDS(gp, lp)                                                        \
  __builtin_amdgcn_global_load_lds(                                               \
      (const __attribute__((address_space(1))) void*)(gp),                        \
      (__attribute__((address_space(3))) void*)(lp), 16, 0, 0)

// 16-lane all-reduce max on the VALU pipe (DPP)
__device__ __forceinline__ float rowmax16(float x) {
#define DPP_MAX(ctrl)                                                             \
  {                                                                               \
    float y = __int_as_float(                                                     \
        __builtin_amdgcn_update_dpp(0, __float_as_int(x), ctrl, 0xF, 0xF, true)); \
    x = fmaxf(x, y);                                                              \
  }
  DPP_MAX(0xB1);   // quad_perm [1,0,3,2]  (xor1)
  DPP_MAX(0x4E);   // quad_perm [2,3,0,1]  (xor2)
  DPP_MAX(0x141);  // row_half_mirror      (xor4 after uniform mod 4)
  DPP_MAX(0x140);  // row_mirror           (xor8 after uniform mod 8)
#undef DPP_MAX
  return x;
}

// ---------------- converts ----------------
__global__ void cvt_f32_to_f16(const float4* __restrict__ in, _Float16* __restrict__ out, int n4) {
  int i = blockIdx.x * blockDim.x + threadIdx.x;
  if (i < n4) {
    float4 v = in[i];
    half4 h;
    h[0] = (_Float16)v.x; h[1] = (_Float16)v.y; h[2] = (_Float16)v.z; h[3] = (_Float16)v.w;
    *(half4*)(out + (size_t)i * 4) = h;
  }
}

// in [K=1280 x N] fp32 row-major -> out [N x 1280] f16, LDS-tiled (coalesced both sides)
template <int N>
__global__ void cvt_transpose_f16(const float* __restrict__ in, _Float16* __restrict__ out) {
  __shared__ float tile[32][33];
  const int tx = threadIdx.x & 31, ty = threadIdx.x >> 5;  // 256 thr: ty 0..7
  const int k0 = blockIdx.y * 32;
  const int n0 = blockIdx.x * 32;
#pragma unroll
  for (int j = 0; j < 4; ++j)
    tile[ty + 8 * j][tx] = in[(size_t)(k0 + ty + 8 * j) * N + n0 + tx];
  __syncthreads();
#pragma unroll
  for (int j = 0; j < 4; ++j)
    out[(size_t)(n0 + ty + 8 * j) * 1280 + k0 + tx] = (_Float16)tile[tx][ty + 8 * j];
}

// ---------------- 256x256 GEMM, 2 barriers/K-tile, wave-internal ds_read<->MFMA overlap ----
// (unchanged from R4 — verified 238 -> <190 us; see R4 hazard ledger)

#define STAGE_A(H, T, D)                                                           \
  do {                                                                             \
    GLD_TO_LDS(aSrc0 + (size_t)((H) * 128) * 1280 + (T) * 64,                      \
               &sA[D][((H) * 128 + wave * 16) * 64]);                              \
    GLD_TO_LDS(aSrc0 + (size_t)((H) * 128 + 8) * 1280 + (T) * 64,                  \
               &sA[D][((H) * 128 + wave * 16 + 8) * 64]);                          \
  } while (0)

#define STAGE_B(H, T, D)                                                           \
  do {                                                                             \
    GLD_TO_LDS(bSrc0 + (size_t)((H) * 128) * 1280 + (T) * 64,                      \
               &sB[D][((H) * 128 + wave * 16) * 64]);                              \
    GLD_TO_LDS(bSrc0 + (size_t)((H) * 128 + 8) * 1280 + (T) * 64,                  \
               &sB[D][((H) * 128 + wave * 16 + 8) * 64]);                          \
  } while (0)

#define LDS_FRAG(P, ROWB, FR, KK) (*(const half8*)((P) + ((ROWB) + (FR) * 16) * 64 + cofs[KK]))

#define MFMA_Q(MIB, NIB)                                                           \
  _Pragma("unroll") for (int mi = 0; mi < 4; ++mi)                                 \
    _Pragma("unroll") for (int ni = 0; ni < 2; ++ni)                               \
      _Pragma("unroll") for (int kk = 0; kk < 2; ++kk)                             \
        acc[(MIB) + mi][(NIB) + ni] = __builtin_amdgcn_mfma_f32_16x16x32_f16(      \
            af[mi][kk], bf[(NIB) + ni][kk], acc[(MIB) + mi][(NIB) + ni], 0, 0, 0)

#define GBODY2(T, D, SA, SB, VNSTR)                                                \
  {                                                                                \
    const _Float16* pA = &sA[D][0];                                                \
    const _Float16* pB = &sB[D][0];                                                \
    if (SA) { STAGE_A(0, (T) + 1, (D) ^ 1); STAGE_A(1, (T) + 1, (D) ^ 1); }        \
    _Pragma("unroll") for (int mi = 0; mi < 4; ++mi)                               \
      _Pragma("unroll") for (int kk = 0; kk < 2; ++kk)                             \
        af[mi][kk] = LDS_FRAG(pA, rA, mi, kk);                                     \
    _Pragma("unroll") for (int ni = 0; ni < 4; ++ni)                               \
      _Pragma("unroll") for (int kk = 0; kk < 2; ++kk)                             \
        bf[ni][kk] = LDS_FRAG(pB, rB, ni, kk);                                     \
    __builtin_amdgcn_s_setprio(1);                                                 \
    MFMA_Q(0, 0);                                                                  \
    MFMA_Q(0, 2);                                                                  \
    __builtin_amdgcn_s_setprio(0);                                                 \
    _Pragma("unroll") for (int mi = 0; mi < 4; ++mi)                               \
      _Pragma("unroll") for (int kk = 0; kk < 2; ++kk)                             \
        af[mi][kk] = LDS_FRAG(pA, rA, 4 + mi, kk);                                 \
    __builtin_amdgcn_s_barrier();                                                  \
    if (SB) { STAGE_B(0, (T) + 2, (D)); STAGE_B(1, (T) + 2, (D)); }                \
    __builtin_amdgcn_s_setprio(1);                                                 \
    MFMA_Q(4, 0);                                                                  \
    MFMA_Q(4, 2);                                                                  \
    __builtin_amdgcn_s_setprio(0);                                                 \
    asm volatile("s_waitcnt " VNSTR ::: "memory");                                 \
    __builtin_amdgcn_s_barrier();                                                  \
  }

template <int MODE>
__global__ __launch_bounds__(512, 2)
void gemm256(const _Float16* __restrict__ A, const _Float16* __restrict__ Bt,
             const float* __restrict__ bias,
             _Float16* __restrict__ q_pad, _Float16* __restrict__ k_pad,
             _Float16* __restrict__ v_t, float* __restrict__ outf) {
  __shared__ __align__(16) _Float16 sA[2][256 * 64];  // 64 KiB
  __shared__ __align__(16) _Float16 sB[2][256 * 64];  // 64 KiB

  const int tid = threadIdx.x;
  const int wave = tid >> 6, lane = tid & 63, quad = lane >> 4, r16 = lane & 15;
  const int wm = wave >> 2, wn = wave & 3;

  // XCD-contiguous swizzle: 64 m-tiles = 8 XCDs x 8; grid %% 8 == 0 for both MODEs.
  const int pid = blockIdx.x;
  const int xcd = pid & 7, local = pid >> 3;
  const int mt = xcd * 8 + (local & 7);
  const int nt = local >> 3;
  const int m0 = mt * 256, n0 = nt * 256;

  // staging source: row_local = wave*16 + i*8 + (lane>>3); chunk = (lane&7) ^ (lane>>3)
  const int l8 = lane >> 3, cg = (lane & 7) ^ l8;
  const _Float16* aSrc0 = A + ((size_t)m0 + wave * 16 + l8) * 1280 + cg * 8;
  const _Float16* bSrc0 = Bt + ((size_t)n0 + wave * 16 + l8) * 1280 + cg * 8;

  // fragment read bases (row&7 == r16&7 since frag rows are 16-aligned + r16)
  const int rA = wm * 128 + r16;
  const int rB = wn * 64 + r16;
  const int cofs[2] = { ((0 + quad) ^ (r16 & 7)) * 8, ((4 + quad) ^ (r16 & 7)) * 8 };

  floatx4 acc[8][4] = {};
  half8 af[4][2], bf[4][2];

  // prologue: tile0 full + B(1); A(1) is staged in tile0's early slot
  STAGE_A(0, 0, 0); STAGE_A(1, 0, 0); STAGE_B(0, 0, 0); STAGE_B(1, 0, 0);
  STAGE_B(0, 1, 1); STAGE_B(1, 1, 1);
  asm volatile("s_waitcnt vmcnt(4)" ::: "memory");  // tile0 landed; B(1) may be in flight
  __builtin_amdgcn_s_barrier();

  for (int it = 0; it < 9; ++it) {
    GBODY2(2 * it, 0, true, true, "vmcnt(4)");
    GBODY2(2 * it + 1, 1, true, true, "vmcnt(4)");
  }
  GBODY2(18, 0, true, false, "vmcnt(0)");   // drain: A(19)+B(19) must land
  GBODY2(19, 1, false, false, "vmcnt(0)");

  // ---------------- epilogue ----------------
  if (MODE == 1) {
#pragma unroll
    for (int mi = 0; mi < 8; ++mi)
#pragma unroll
      for (int ni = 0; ni < 4; ++ni) {
        int n = n0 + wn * 64 + ni * 16 + r16;
        float bv = bias[n];
#pragma unroll
        for (int r = 0; r < 4; ++r) {
          int m = m0 + wm * 128 + mi * 16 + quad * 4 + r;
          outf[(size_t)m * EMBED + n] = acc[mi][ni][r] + bv;
        }
      }
  } else {
#pragma unroll
    for (int mi = 0; mi < 8; ++mi)
#pragma unroll
      for (int ni = 0; ni < 4; ++ni) {
        int n = n0 + wn * 64 + ni * 16 + r16;
        float bv = bias[n];
        int which = n / 1280;
        int rem = n - which * 1280;
        int h = rem / 80;
        int d = rem - h * 80;
        int mbase = m0 + wm * 128 + mi * 16 + quad * 4;  // 4-aligned, never crosses SEQ
        int b = mbase >> 10, s = mbase & 1023;
        int bh = b * NH + h;
        if (which == 2) {
          // v_t[bh][d][s]: 4 consecutive s per lane -> one 8B store (was 4x 2B scatter)
          half4 pv;
#pragma unroll
          for (int r = 0; r < 4; ++r) pv[r] = (_Float16)(acc[mi][ni][r] + bv);
          *(half4*)(v_t + ((size_t)bh * HD + d) * SEQ + s) = pv;
        } else {
          _Float16* dst = (which == 0) ? q_pad : k_pad;
#pragma unroll
          for (int r = 0; r < 4; ++r) {
            _Float16 val = (_Float16)(acc[mi][ni][r] + bv);
            dst[((size_t)bh * SEQ + (s + r)) * HDP + d] = val;
            if (d < 16) dst[((size_t)bh * SEQ + (s + r)) * HDP + 80 + d] = (_Float16)0.f;
          }
        }
      }
  }
}

// ---------------- flash attention (dbuf K/V + async-stage, bh-major XCD mapping) ----
// grid 2048 blocks, 256 thr. R5: bh = bid & 255, qt = bid >> 8 -> the 8 q-tile blocks
// sharing one bh's K/V have identical bid%8 -> SAME XCD -> K/V panel cached once in
// that XCD's L2 (was: spread over 8 XCDs, 8 L2 copies, 2.7x HBM over-fetch).
// R5: strict defer-rescale -- when the tile max doesn't exceed the running max,
// alpha == 1 exactly; skip the exp2 + 48 muls + mrow update (bit-identical result).
__global__ __launch_bounds__(256, 2)
void attn_kernel(const _Float16* __restrict__ q_pad, const _Float16* __restrict__ k_pad,
                 const _Float16* __restrict__ v_t, _Float16* __restrict__ attn_out) {
  __shared__ __align__(16) _Float16 sK[2][64 * SK_STRIDE];   // 26.0 KB
  __shared__ __align__(16) _Float16 sV[2][96 * SV_STRIDE];   // 27.0 KB
  __shared__ __align__(16) _Float16 sP[4][16 * SP_STRIDE];   //  9.0 KB (reused mi=0 then mi=1)

  const int tid = threadIdx.x;
  const int wave = tid >> 6, lane = tid & 63, quad = lane >> 4, r16 = lane & 15;
  const int bh = blockIdx.x & 255;         // bh-major: same bh -> same XCD
  const int q0 = (blockIdx.x >> 8) * 128;

  // static sV rows 80..95 (ones row + zeros) in BOTH buffers; never overwritten in-loop
  if (tid < 128) {
    int row = 80 + (tid >> 3), col = (tid & 7) * 8;
    half8 z;
#pragma unroll
    for (int j = 0; j < 8; ++j) z[j] = (row == 80) ? (_Float16)1.f : (_Float16)0.f;
    *(half8*)(&sV[0][row * SV_STRIDE + col]) = z;
    *(half8*)(&sV[1][row * SV_STRIDE + col]) = z;
  }

  // Q fragments (A-layout), pre-scaled by SCALE*LOG2E (log2-domain softmax)
  half8 qf[2][3];
#pragma unroll
  for (int mi = 0; mi < 2; ++mi) {
    const _Float16* qb = q_pad + ((size_t)bh * SEQ + q0 + wave * 32 + mi * 16 + r16) * HDP;
#pragma unroll
    for (int kq = 0; kq < 3; ++kq) {
      half8 q = *(const half8*)(qb + kq * 32 + quad * 8);
#pragma unroll
      for (int j = 0; j < 8; ++j) q[j] = q[j] * (_Float16)(SCALE * LOG2E);
      qf[mi][kq] = q;
    }
  }

  // per-thread staging slots
  int rowK[3], colK[3];
#pragma unroll
  for (int i = 0; i < 3; ++i) {
    int c = tid + i * 256;
    rowK[i] = c / 12; colK[i] = c - rowK[i] * 12;
  }
  const int rowV0 = tid >> 3, colV0 = tid & 7;
  const _Float16* kgb = k_pad + ((size_t)bh * SEQ) * HDP;
  const _Float16* vgb = v_t + (size_t)bh * HD * SEQ;

  // prologue: stage tile 0 into buf 0
  {
    uint4 tk0 = *(const uint4*)(kgb + (size_t)(rowK[0]) * HDP + colK[0] * 8);
    uint4 tk1 = *(const uint4*)(kgb + (size_t)(rowK[1]) * HDP + colK[1] * 8);
    uint4 tk2 = *(const uint4*)(kgb + (size_t)(rowK[2]) * HDP + colK[2] * 8);
    uint4 tv0 = *(const uint4*)(vgb + (size_t)(rowV0) * SEQ + colV0 * 8);
    uint4 tv1 = *(const uint4*)(vgb + (size_t)(rowV0 + 32) * SEQ + colV0 * 8);
    *(uint4*)(&sK[0][rowK[0] * SK_STRIDE + colK[0] * 8]) = tk0;
    *(uint4*)(&sK[0][rowK[1] * SK_STRIDE + colK[1] * 8]) = tk1;
    *(uint4*)(&sK[0][rowK[2] * SK_STRIDE + colK[2] * 8]) = tk2;
    *(uint4*)(&sV[0][(rowV0)*SV_STRIDE + colV0 * 8]) = tv0;
    *(uint4*)(&sV[0][(rowV0 + 32) * SV_STRIDE + colV0 * 8]) = tv1;
    if (tid < 128) {
      uint4 tv2 = *(const uint4*)(vgb + (size_t)(rowV0 + 64) * SEQ + colV0 * 8);
      *(uint4*)(&sV[0][(rowV0 + 64) * SV_STRIDE + colV0 * 8]) = tv2;
    }
  }

  floatx4 o[2][6] = {};
  float mrow[2][4];
#pragma unroll
  for (int mi = 0; mi < 2; ++mi)
#pragma unroll
    for (int r = 0; r < 4; ++r) mrow[mi][r] = -1e30f;

  __syncthreads();  // tile0 + static rows visible

  for (int kt = 0; kt < 16; ++kt) {
    const int cur = kt & 1, nxt = cur ^ 1;

    // T14 issue-early: global loads for tile kt+1 (held in regs across QK^T)
    uint4 tk0, tk1, tk2, tv0, tv1, tv2;
    if (kt < 15) {
      const int kb = (kt + 1) * 64;
      tk0 = *(const uint4*)(kgb + (size_t)(kb + rowK[0]) * HDP + colK[0] * 8);
      tk1 = *(const uint4*)(kgb + (size_t)(kb + rowK[1]) * HDP + colK[1] * 8);
      tk2 = *(const uint4*)(kgb + (size_t)(kb + rowK[2]) * HDP + colK[2] * 8);
      tv0 = *(const uint4*)(vgb + (size_t)(rowV0)*SEQ + kb + colV0 * 8);
      tv1 = *(const uint4*)(vgb + (size_t)(rowV0 + 32) * SEQ + kb + colV0 * 8);
      if (tid < 128)
        tv2 = *(const uint4*)(vgb + (size_t)(rowV0 + 64) * SEQ + kb + colV0 * 8);
    }

    // S = Q K^T : 32 q-rows x 64 keys per wave (from sK[cur])
    floatx4 sacc[2][4] = {};
    __builtin_amdgcn_s_setprio(1);
#pragma unroll
    for (int ni = 0; ni < 4; ++ni)
#pragma unroll
      for (int kq = 0; kq < 3; ++kq) {
        half8 kf = *(const half8*)(&sK[cur][(ni * 16 + r16) * SK_STRIDE + kq * 32 + quad * 8]);
#pragma unroll
        for (int mi = 0; mi < 2; ++mi)
          sacc[mi][ni] = __builtin_amdgcn_mfma_f32_16x16x32_f16(qf[mi][kq], kf, sacc[mi][ni], 0, 0, 0);
      }
    __builtin_amdgcn_s_setprio(0);

    // write-late: publish tile kt+1 into the other buffer (vmcnt inserted by compiler)
    if (kt < 15) {
      *(uint4*)(&sK[nxt][rowK[0] * SK_STRIDE + colK[0] * 8]) = tk0;
      *(uint4*)(&sK[nxt][rowK[1] * SK_STRIDE + colK[1] * 8]) = tk1;
      *(uint4*)(&sK[nxt][rowK[2] * SK_STRIDE + colK[2] * 8]) = tk2;
      *(uint4*)(&sV[nxt][(rowV0)*SV_STRIDE + colV0 * 8]) = tv0;
      *(uint4*)(&sV[nxt][(rowV0 + 32) * SV_STRIDE + colV0 * 8]) = tv1;
      if (tid < 128)
        *(uint4*)(&sV[nxt][(rowV0 + 64) * SV_STRIDE + colV0 * 8]) = tv2;
    }

    // online softmax (log2 domain) with strict defer-rescale:
    // when mx <= mrow, alpha == 1 exactly -> skip exp2 + o-rescale + mrow update.
    // Branch uniform within each 16-lane row group (mx, mrow group-uniform).
#pragma unroll
    for (int mi = 0; mi < 2; ++mi)
#pragma unroll
      for (int r = 0; r < 4; ++r) {
        float mx = fmaxf(fmaxf(sacc[mi][0][r], sacc[mi][1][r]),
                         fmaxf(sacc[mi][2][r], sacc[mi][3][r]));
        mx = rowmax16(mx);
        if (mx > mrow[mi][r]) {
          float alpha = __builtin_amdgcn_exp2f(mrow[mi][r] - mx);
          mrow[mi][r] = mx;
#pragma unroll
          for (int di = 0; di < 6; ++di) o[mi][di][r] *= alpha;
        }
        float m = mrow[mi][r];
#pragma unroll
        for (int ni = 0; ni < 4; ++ni)
          sacc[mi][ni][r] = __builtin_amdgcn_exp2f(sacc[mi][ni][r] - m);
      }

    // P: C-layout -> A-layout via per-wave LDS buffer, reused across mi
    // (same-wave DS ops complete in order -> no barrier needed between mi phases)
#pragma unroll
    for (int mi = 0; mi < 2; ++mi) {
#pragma unroll
      for (int ni = 0; ni < 4; ++ni)
#pragma unroll
        for (int r = 0; r < 4; ++r)
          sP[wave][(quad * 4 + r) * SP_STRIDE + ni * 16 + r16] = (_Float16)sacc[mi][ni][r];
#pragma unroll
      for (int kp = 0; kp < 2; ++kp) {
        half8 pf = *(const half8*)(&sP[wave][r16 * SP_STRIDE + kp * 32 + quad * 8]);
        __builtin_amdgcn_s_setprio(1);
#pragma unroll
        for (int di = 0; di < 6; ++di) {
          half8 vf = *(const half8*)(&sV[cur][(di * 16 + r16) * SV_STRIDE + kp * 32 + quad * 8]);
          o[mi][di] = __builtin_amdgcn_mfma_f32_16x16x32_f16(pf, vf, o[mi][di], 0, 0, 0);
        }
        __builtin_amdgcn_s_setprio(0);
      }
    }

    __syncthreads();  // buf[cur] free for kt+2's stage; buf[nxt] published
  }

  // epilogue: l = o[mi][5] col 80 lives in r16==0 lane of each 16-group
  const int b = bh >> 4, h = bh & 15;
#pragma unroll
  for (int mi = 0; mi < 2; ++mi)
#pragma unroll
    for (int r = 0; r < 4; ++r) {
      float l = __shfl(o[mi][5][r], lane & 48);
      float inv = 1.0f / l;
      int tok = b * SEQ + q0 + wave * 32 + mi * 16 + quad * 4 + r;
#pragma unroll
      for (int di = 0; di < 5; ++di) {
        int e = h * HD + di * 16 + r16;
        attn_out[(size_t)tok * EMBED + e] = (_Float16)(o[mi][di][r] * inv);
      }
    }
}

// ---------------- launch ----------------
extern "C" void kernel_launch(void* const* d_in, const int* in_sizes, int n_in,
                              void* d_out, int out_size, void* d_ws, size_t ws_size,
                              hipStream_t stream) {
  const float* hidden = (const float*)d_in[0];
  const float* w_qkv  = (const float*)d_in[1];
  const float* b_qkv  = (const float*)d_in[2];
  const float* w_proj = (const float*)d_in[3];
  const float* b_proj = (const float*)d_in[4];
  float* out = (float*)d_out;

  char* ws = (char*)d_ws;
  size_t off = 0;
  _Float16* hidden_h = (_Float16*)(ws + off); off += (size_t)MTOK * EMBED * 2;
  _Float16* wqkv_t   = (_Float16*)(ws + off); off += (size_t)NQKV * EMBED * 2;
  _Float16* wproj_t  = (_Float16*)(ws + off); off += (size_t)EMBED * EMBED * 2;
  _Float16* q_pad    = (_Float16*)(ws + off); off += (size_t)BATCH * NH * SEQ * HDP * 2;
  _Float16* k_pad    = (_Float16*)(ws + off); off += (size_t)BATCH * NH * SEQ * HDP * 2;
  _Float16* v_t      = (_Float16*)(ws + off); off += (size_t)BATCH * NH * HD * SEQ * 2;
  _Float16* attn_out = hidden_h;  // alias: hidden_h consumed before attention writes

  {
    int n4 = MTOK * EMBED / 4;
    cvt_f32_to_f16<<<(n4 + 255) / 256, 256, 0, stream>>>((const float4*)hidden, hidden_h, n4);
  }
  cvt_transpose_f16<NQKV><<<dim3(NQKV / 32, 1280 / 32), 256, 0, stream>>>(w_qkv, wqkv_t);
  cvt_transpose_f16<EMBED><<<dim3(EMBED / 32, 1280 / 32), 256, 0, stream>>>(w_proj, wproj_t);

  // QKV projection: M=16384, N=3840 -> 64 x 15 = 960 blocks (960 % 8 == 0)
  gemm256<0><<<960, 512, 0, stream>>>(hidden_h, wqkv_t, b_qkv, q_pad, k_pad, v_t, nullptr);

  attn_kernel<<<BATCH * NH * (SEQ / 128), 256, 0, stream>>>(q_pad, k_pad, v_t, attn_out);

  // output projection: M=16384, N=1280 -> 64 x 5 = 320 blocks (320 % 8 == 0)
  gemm256<1><<<320, 512, 0, stream>>>(attn_out, wproj_t, b_proj, nullptr, nullptr, nullptr, out);
}